// Round 9
// baseline (760.157 us; speedup 1.0000x reference)
//
#include <hip/hip_runtime.h>
#include <hip/hip_bf16.h>

#define N_NODES 100000
#define N_EDGES 1600000
#define N_GRAPHS 1024
#define BSZ 1024
#define EPS 1e-5f

#define NBUCK 256
#define BUCKW 391          // ceil(100000/256)
#define BCAP  8192         // static per-bucket edge capacity (mean 6250, sd 79)
#define SRC_MASK 0x1FFFF   // 17 bits for src (<131072)
#define BIN_CHUNK 4096
#define BIN_BLOCKS 391     // ceil(1600000/4096)
#define NCHUNK 512         // moment row-chunks
#define CHUNK_ROWS 196     // 512*196 = 100352 >= 100000
#define WINW 98            // gather window nodes (4 windows/bucket)
#define NWIN 4
#define CVT_BLOCKS 6250    // 100000*64/4/256

// ---------------- workspace layout (4-byte units) ----------------
// zeroed-every-call region:
#define WS_PSUM    0          // 1024*128 pooled sums
#define WS_STATS1  131072     // 128
#define WS_STATS2  131200     // 128
#define WS_STATS4  131328     // 512
#define WS_STATS5  131840     // 128
#define WS_M       131968     // 4096 (aggx^T aggx)
#define WS_CS      136064     // 64 (aggx column sums)
#define WS_ZTOTAL  136128
// written-before-read region:
#define WS_GCUR    136128     // 256 int (init to b*BCAP by prep)
#define WS_SCALE1  136384     // 128
#define WS_SHIFTP  136512     // 128
#define WS_GSTART  136640     // 1025 int (pad to 137668)
#define WS_DIS     137668     // 100000 float -> 237668
#define WS_PACKED  237668     // 256*8192 u32 -> 2334820
#define WS_XH      2334820    // 100000*64 ushort = 3200000 words -> 5534820
#define WS_AGGX    5534820    // 100000*64 -> 11934820
#define WS_T1      11934820   // 1024*64 -> 12000356
#define WS_T2      12000356   // 1024*64 -> 12065892
#define WS_T4      12065892   // 1024*256 -> 12328036
#define WS_T5      12328036   // 1024*64 -> 12393572
// total = 12393572 words = ~49.6 MB

__device__ inline unsigned short f2bf(float f) {
    unsigned int u = __float_as_uint(f);
    return (unsigned short)((u + 0x7FFFu + ((u >> 16) & 1u)) >> 16);
}

// blocks 0..6249: fp32->bf16 convert; 6250..6265: zero; 6266: gcur; 6267..6270: graph bounds
__global__ __launch_bounds__(256) void prep_cvt_kernel(float* __restrict__ ws,
                                                       const int* __restrict__ gbatch,
                                                       const float* __restrict__ x,
                                                       unsigned short* __restrict__ xh) {
    int b = blockIdx.x, tid = threadIdx.x;
    if (b < CVT_BLOCKS) {
        int i = b * 256 + tid;
        float4 f = ((const float4*)x)[i];
        ushort4 h;
        h.x = f2bf(f.x); h.y = f2bf(f.y); h.z = f2bf(f.z); h.w = f2bf(f.w);
        ((ushort4*)xh)[i] = h;
    } else if (b < CVT_BLOCKS + 16) {
        for (int i = (b - CVT_BLOCKS) * 256 + tid; i < WS_ZTOTAL; i += 16 * 256) ws[i] = 0.0f;
    } else if (b == CVT_BLOCKS + 16) {
        ((int*)(ws + WS_GCUR))[tid] = tid * BCAP;
    } else {
        int g = (b - (CVT_BLOCKS + 17)) * 256 + tid;
        int lo = 0, hi = N_NODES;
        while (lo < hi) {
            int mid = (lo + hi) >> 1;
            if (gbatch[mid] < g) lo = mid + 1; else hi = mid;
        }
        int* gstart = (int*)(ws + WS_GSTART);
        gstart[g] = lo;
        if (g == 0) gstart[N_GRAPHS] = N_NODES;
    }
}

// bin edges into 256 coarse dst-buckets (static BCAP stride) with LDS staging
__global__ __launch_bounds__(512) void bin_kernel(const int* __restrict__ ei,
                                                  int* __restrict__ gcursor,
                                                  unsigned int* __restrict__ packed) {
    __shared__ unsigned int stage[BIN_CHUNK];   // 16KB
    __shared__ int lh[NBUCK], lbase[NBUCK], lcur[NBUCK], gb[NBUCK];
    const int* src = ei;
    const int* dst = ei + N_EDGES;
    int tid = threadIdx.x;
    int base = blockIdx.x * BIN_CHUNK;
    int n = min(BIN_CHUNK, N_EDGES - base);
    if (tid < NBUCK) lh[tid] = 0;
    __syncthreads();
    for (int i = tid; i < n; i += 512)
        atomicAdd(&lh[dst[base + i] / BUCKW], 1);
    __syncthreads();
    if (tid < NBUCK) lbase[tid] = lh[tid];
    __syncthreads();
    for (int off = 1; off < NBUCK; off <<= 1) {
        int t = (tid < NBUCK && tid >= off) ? lbase[tid - off] : 0;
        __syncthreads();
        if (tid < NBUCK) lbase[tid] += t;
        __syncthreads();
    }
    if (tid < NBUCK) {
        int excl = lbase[tid] - lh[tid];
        lbase[tid] = excl;
        lcur[tid] = excl;
        gb[tid] = atomicAdd(&gcursor[tid], lh[tid]);
    }
    __syncthreads();
    for (int i = tid; i < n; i += 512) {
        int d = dst[base + i];
        int s = src[base + i];
        int bk = d / BUCKW;
        int dl = d - bk * BUCKW;
        int slot = atomicAdd(&lcur[bk], 1);
        stage[slot] = ((unsigned int)dl << 17) | (unsigned int)s;
    }
    __syncthreads();
    int wid = tid >> 6, lane = tid & 63;
    for (int bk = wid; bk < NBUCK; bk += 8) {
        int lo = lbase[bk], go = gb[bk];
        int len = min(lh[bk], (bk + 1) * BCAP - go);  // overflow clamp (never expected)
        for (int j = lane; j < len; j += 64)
            packed[go + j] = stage[lo + j];
    }
}

// per-bucket degree histogram -> dis = rsqrt(deg+1)
__global__ __launch_bounds__(256) void degdis_kernel(const unsigned int* __restrict__ packed,
                                                     const int* __restrict__ gcur,
                                                     float* __restrict__ dis) {
    __shared__ int dcnt[BUCKW];
    int b = blockIdx.x, tid = threadIdx.x;
    int e0 = b * BCAP;
    int ecnt = min(gcur[b] - e0, BCAP);
    int nbase = b * BUCKW;
    int nmax = min(BUCKW, N_NODES - nbase);
    for (int i = tid; i < BUCKW; i += 256) dcnt[i] = 0;
    __syncthreads();
    for (int i = tid; i < ecnt; i += 256)
        atomicAdd(&dcnt[packed[e0 + i] >> 17], 1);
    __syncthreads();
    for (int i = tid; i < nmax; i += 256)
        dis[nbase + i] = rsqrtf((float)dcnt[i] + 1.0f);
}

// windowed filter-gather: one block per (bucket, 98-node window); LDS float-atomic acc.
// aggx[n] = xh[n]*dis[n]^2 + sum_{s in in(n)} xh[s]*dis[s]*dis[n]
__global__ __launch_bounds__(512) void gather_kernel(const unsigned short* __restrict__ xh,
                                                     const unsigned int* __restrict__ packed,
                                                     const int* __restrict__ gcur,
                                                     const float* __restrict__ dis,
                                                     float* __restrict__ aggx) {
    __shared__ float acc[WINW * 64];   // 25.1KB
    __shared__ float disw[WINW];
    int blk = blockIdx.x;
    int b = blk >> 2;
    int w = blk & 3;
    int wlo = w * WINW;
    int nbase = b * BUCKW + wlo;
    int nwin = min(WINW, min(BUCKW - wlo, N_NODES - nbase));
    if (nwin <= 0) return;   // block-uniform exit
    int tid = threadIdx.x;
    int lane = tid & 63, wave = tid >> 6;
    for (int i = tid; i < WINW * 64; i += 512) acc[i] = 0.f;
    if (tid < nwin) disw[tid] = dis[nbase + tid];
    __syncthreads();
    int e0 = b * BCAP;
    int ecnt = min(gcur[b] - e0, BCAP);
    int whi = wlo + nwin;
    for (int c0 = wave * 64; c0 < ecnt; c0 += 512) {
        int n = min(64, ecnt - c0);
        unsigned int rec = (lane < n) ? packed[e0 + c0 + lane] : 0xFFFFFFFFu;
        int dl = (int)(rec >> 17);          // sentinel -> 32767 (filtered)
        bool m = (dl >= wlo) && (dl < whi);
        float wv = m ? dis[rec & SRC_MASK] : 0.f;
        unsigned long long mask = __ballot(m);
        while (mask) {
            int p = __ffsll(mask) - 1;
            mask &= mask - 1;
            unsigned int r = __shfl(rec, p);
            float ws = __shfl(wv, p);
            int dloc = (int)(r >> 17) - wlo;
            int s = (int)(r & SRC_MASK);
            float v = __uint_as_float((unsigned int)xh[(size_t)s * 64 + lane] << 16);
            atomicAdd(&acc[dloc * 64 + lane], v * (ws * disw[dloc]));
        }
    }
    __syncthreads();
    for (int nl = wave; nl < nwin; nl += 8) {
        int node = nbase + nl;
        float dd = disw[nl];
        float self = __uint_as_float((unsigned int)xh[(size_t)node * 64 + lane] << 16);
        aggx[(size_t)node * 64 + lane] = acc[nl * 64 + lane] + self * dd * dd;
    }
}

// partial second moments, atomically accumulated into M[64][64] and CS[64]
__global__ __launch_bounds__(256) void moment_kernel(const float* __restrict__ aggx,
                                                     float* __restrict__ M,
                                                     float* __restrict__ CS) {
    __shared__ float rows[8 * 64];
    int c = blockIdx.x, tid = threadIdx.x;
    int r0 = c * CHUNK_ROWS;
    int r1 = min(r0 + CHUNK_ROWS, N_NODES);
    int i0 = (tid >> 6) * 16;
    int j = tid & 63;
    float acc[16] = {};
    float cs = 0.f;
    for (int it = 0; it < (CHUNK_ROWS + 7) / 8; ++it) {
        int sid = tid * 2;
        int grow = r0 + it * 8 + (sid >> 6);
        float2 v = {0.f, 0.f};
        if (grow < r1) v = *(const float2*)(aggx + (size_t)(r0 + it * 8) * 64 + sid);
        __syncthreads();
        *(float2*)(rows + sid) = v;
        __syncthreads();
#pragma unroll
        for (int rr = 0; rr < 8; ++rr) {
            float bj = rows[rr * 64 + j];
            float4 a0 = *(const float4*)(rows + rr * 64 + i0);
            float4 a1 = *(const float4*)(rows + rr * 64 + i0 + 4);
            float4 a2 = *(const float4*)(rows + rr * 64 + i0 + 8);
            float4 a3 = *(const float4*)(rows + rr * 64 + i0 + 12);
            acc[0]  += a0.x * bj; acc[1]  += a0.y * bj; acc[2]  += a0.z * bj; acc[3]  += a0.w * bj;
            acc[4]  += a1.x * bj; acc[5]  += a1.y * bj; acc[6]  += a1.z * bj; acc[7]  += a1.w * bj;
            acc[8]  += a2.x * bj; acc[9]  += a2.y * bj; acc[10] += a2.z * bj; acc[11] += a2.w * bj;
            acc[12] += a3.x * bj; acc[13] += a3.y * bj; acc[14] += a3.z * bj; acc[15] += a3.w * bj;
        }
        if (tid < 64) {
#pragma unroll
            for (int rr = 0; rr < 8; ++rr) cs += rows[rr * 64 + tid];
        }
    }
#pragma unroll
    for (int m = 0; m < 16; ++m)
        unsafeAtomicAdd(&M[(i0 + m) * 64 + j], acc[m]);
    if (tid < 64) unsafeAtomicAdd(&CS[tid], cs);
}

// folded BN1 scale/shift: one block per output column j, 64 threads, no per-thread arrays
__global__ __launch_bounds__(64) void fold_kernel(const float* __restrict__ M,
                                                  const float* __restrict__ CS,
                                                  const float* __restrict__ W,
                                                  const float* __restrict__ g1,
                                                  const float* __restrict__ be1,
                                                  float* __restrict__ scale1,
                                                  float* __restrict__ shiftp) {
    __shared__ float wcol[64];
    int j = blockIdx.x;
    int lane = threadIdx.x;
    wcol[lane] = W[lane * 128 + j];
    __syncthreads();
    float wl = wcol[lane];
    float t = 0.f;
    const float* Mrow = M + lane * 64;
#pragma unroll 16
    for (int k = 0; k < 64; ++k) t += Mrow[k] * wcol[k];
    float part = t * wl;
    float csp = CS[lane] * wl;
#pragma unroll
    for (int off = 32; off; off >>= 1) {
        part += __shfl_xor(part, off);
        csp  += __shfl_xor(csp, off);
    }
    if (lane == 0) {
        float Ey2 = part * (1.0f / N_NODES);
        float my = csp * (1.0f / N_NODES);
        float var = Ey2 - my * my;
        float sc = g1[j] * rsqrtf(var + EPS);
        scale1[j] = sc;
        shiftp[j] = be1[j] - my * sc;
    }
}

// fused: y = aggx_tile @ W, z = relu(y*sc+sh), segment-run atomicAdd into psum[g][c]
__global__ __launch_bounds__(256) void gemm_pool_kernel(const float* __restrict__ aggx,
                                                        const int* __restrict__ gbatch,
                                                        const float* __restrict__ W,
                                                        const float* __restrict__ scale1,
                                                        const float* __restrict__ shiftp,
                                                        float* __restrict__ psum) {
    __shared__ float Ws[64 * 128];   // 32KB
    __shared__ float As[16 * 64];    // 4KB
    __shared__ float Zs[16 * 128];   // 8KB
    __shared__ int gid[16];
    int tid = threadIdx.x;
    const float4* W4 = (const float4*)W;
    float4* Ws4 = (float4*)Ws;
#pragma unroll
    for (int i = 0; i < 8; ++i) Ws4[tid + i * 256] = W4[tid + i * 256];
    int row0 = blockIdx.x * 16;
    ((float4*)As)[tid] = ((const float4*)(aggx + (size_t)row0 * 64))[tid];
    if (tid < 16) gid[tid] = gbatch[row0 + tid];
    __syncthreads();
    int tx = tid & 31;
    int ty = tid >> 5;
    int r0 = ty * 2;
    float4 sc4 = ((const float4*)scale1)[tx];
    float4 sh4 = ((const float4*)shiftp)[tx];
    float acc[2][4] = {};
#pragma unroll
    for (int k = 0; k < 64; ++k) {
        float a0 = As[r0 * 64 + k];
        float a1 = As[(r0 + 1) * 64 + k];
        float4 w = Ws4[k * 32 + tx];
        acc[0][0] += a0 * w.x; acc[0][1] += a0 * w.y; acc[0][2] += a0 * w.z; acc[0][3] += a0 * w.w;
        acc[1][0] += a1 * w.x; acc[1][1] += a1 * w.y; acc[1][2] += a1 * w.z; acc[1][3] += a1 * w.w;
    }
#pragma unroll
    for (int rr = 0; rr < 2; ++rr) {
        float4 z;
        z.x = fmaxf(acc[rr][0] * sc4.x + sh4.x, 0.f);
        z.y = fmaxf(acc[rr][1] * sc4.y + sh4.y, 0.f);
        z.z = fmaxf(acc[rr][2] * sc4.z + sh4.z, 0.f);
        z.w = fmaxf(acc[rr][3] * sc4.w + sh4.w, 0.f);
        ((float4*)(Zs + (r0 + rr) * 128))[tx] = z;
    }
    __syncthreads();
    if (tid < 128) {
        int c = tid;
        float a = 0.f;
        int g = gid[0];
#pragma unroll
        for (int i = 0; i < 16; ++i) {
            int gi = gid[i];
            if (gi != g) {
                unsafeAtomicAdd(&psum[(size_t)g * 128 + c], a);
                a = 0.f;
                g = gi;
            }
            a += Zs[i * 128 + c];
        }
        unsafeAtomicAdd(&psum[(size_t)g * 128 + c], a);
    }
}

// t1 = (psum/cnt) @ W_lin1 + b ; stats1 += (sum, sumsq)
__global__ __launch_bounds__(256) void lin1_kernel(const float* __restrict__ psum,
                                                   const int* __restrict__ gstart,
                                                   const float* __restrict__ W,
                                                   const float* __restrict__ bias,
                                                   float* __restrict__ t1,
                                                   float* __restrict__ stats1) {
    __shared__ float ls[256], ls2[256];
    int tid = threadIdx.x;
    int r = blockIdx.x * 4 + (tid >> 6);
    int c = tid & 63;
    float invc = 1.0f / fmaxf((float)(gstart[r + 1] - gstart[r]), 1.0f);
    float acc = 0.f;
    const float* srow = psum + (size_t)r * 128;
#pragma unroll 8
    for (int k = 0; k < 128; ++k)
        acc += srow[k] * W[k * 64 + c];
    acc = bias[c] + acc * invc;
    t1[r * 64 + c] = acc;
    ls[tid] = acc; ls2[tid] = acc * acc;
    __syncthreads();
    if (tid < 64) {
        float s = ls[tid] + ls[tid + 64] + ls[tid + 128] + ls[tid + 192];
        float q = ls2[tid] + ls2[tid + 64] + ls2[tid + 128] + ls2[tid + 192];
        unsafeAtomicAdd(&stats1[c], s);
        unsafeAtomicAdd(&stats1[64 + c], q);
    }
}

// t2 = relu(bn(t1; g2,be2)) @ W_lin2 + b ; stats2
__global__ __launch_bounds__(256) void lin2_kernel(const float* __restrict__ t1,
                                                   const float* __restrict__ stats1,
                                                   const float* __restrict__ g,
                                                   const float* __restrict__ be,
                                                   const float* __restrict__ W,
                                                   const float* __restrict__ bias,
                                                   float* __restrict__ t2,
                                                   float* __restrict__ stats2) {
    __shared__ float sc[64], sh[64];
    __shared__ float ls[256], ls2[256];
    int tid = threadIdx.x;
    if (tid < 64) {
        float m = stats1[tid] * (1.0f / BSZ);
        float var = stats1[64 + tid] * (1.0f / BSZ) - m * m;
        float s = g[tid] * rsqrtf(var + EPS);
        sc[tid] = s; sh[tid] = be[tid] - m * s;
    }
    __syncthreads();
    int r = blockIdx.x * 4 + (tid >> 6);
    int c = tid & 63;
    float acc = bias[c];
    const float* row = t1 + (size_t)r * 64;
#pragma unroll 8
    for (int k = 0; k < 64; ++k) {
        float z = fmaxf(row[k] * sc[k] + sh[k], 0.f);
        acc += z * W[k * 64 + c];
    }
    t2[r * 64 + c] = acc;
    ls[tid] = acc; ls2[tid] = acc * acc;
    __syncthreads();
    if (tid < 64) {
        float s = ls[tid] + ls[tid + 64] + ls[tid + 128] + ls[tid + 192];
        float q = ls2[tid] + ls2[tid + 64] + ls2[tid + 128] + ls2[tid + 192];
        unsafeAtomicAdd(&stats2[c], s);
        unsafeAtomicAdd(&stats2[64 + c], q);
    }
}

// t4 = concat(x, bn(t2;g3,be3)[masks]) @ W_fc1 + b ; stats4
__global__ __launch_bounds__(1024) void fc1_kernel(const float* __restrict__ x,
                                                   const int* __restrict__ masks,
                                                   const float* __restrict__ t2,
                                                   const float* __restrict__ stats2,
                                                   const float* __restrict__ g3,
                                                   const float* __restrict__ be3,
                                                   const float* __restrict__ W,
                                                   const float* __restrict__ bias,
                                                   float* __restrict__ t4,
                                                   float* __restrict__ stats4) {
    __shared__ float sc[64], sh[64];
    __shared__ float cat[4][128];
    __shared__ float ls[1024], ls2[1024];
    int tid = threadIdx.x;
    if (tid < 64) {
        float m = stats2[tid] * (1.0f / BSZ);
        float var = stats2[64 + tid] * (1.0f / BSZ) - m * m;
        float s = g3[tid] * rsqrtf(var + EPS);
        sc[tid] = s; sh[tid] = be3[tid] - m * s;
    }
    __syncthreads();
    int r0 = blockIdx.x * 4;
    if (tid < 512) {
        int i = tid >> 7;
        int k = tid & 127;
        int r = r0 + i;
        float v;
        if (k < 64) {
            v = x[r * 64 + k];
        } else {
            int mrow = masks[r];
            int kk = k - 64;
            v = t2[mrow * 64 + kk] * sc[kk] + sh[kk];
        }
        cat[i][k] = v;
    }
    __syncthreads();
    int i = tid >> 8;
    int c = tid & 255;
    float acc = bias[c];
#pragma unroll 8
    for (int k = 0; k < 128; ++k)
        acc += cat[i][k] * W[k * 256 + c];
    t4[(size_t)(r0 + i) * 256 + c] = acc;
    ls[tid] = acc; ls2[tid] = acc * acc;
    __syncthreads();
    if (tid < 256) {
        float s = ls[tid] + ls[tid + 256] + ls[tid + 512] + ls[tid + 768];
        float q = ls2[tid] + ls2[tid + 256] + ls2[tid + 512] + ls2[tid + 768];
        unsafeAtomicAdd(&stats4[c], s);
        unsafeAtomicAdd(&stats4[256 + c], q);
    }
}

// t5 = (relu(bn(t4;g4,be4))^2) @ W_fc2 + b ; stats5
__global__ __launch_bounds__(256) void fc2_kernel(const float* __restrict__ t4,
                                                  const float* __restrict__ stats4,
                                                  const float* __restrict__ g4,
                                                  const float* __restrict__ be4,
                                                  const float* __restrict__ W,
                                                  const float* __restrict__ bias,
                                                  float* __restrict__ t5,
                                                  float* __restrict__ stats5) {
    __shared__ float sc[256], sh[256];
    __shared__ float ls[256], ls2[256];
    int tid = threadIdx.x;
    {
        float m = stats4[tid] * (1.0f / BSZ);
        float var = stats4[256 + tid] * (1.0f / BSZ) - m * m;
        float s = g4[tid] * rsqrtf(var + EPS);
        sc[tid] = s; sh[tid] = be4[tid] - m * s;
    }
    __syncthreads();
    int r = blockIdx.x * 4 + (tid >> 6);
    int c = tid & 63;
    float acc = bias[c];
    const float* row = t4 + (size_t)r * 256;
#pragma unroll 8
    for (int k = 0; k < 256; ++k) {
        float z = fmaxf(row[k] * sc[k] + sh[k], 0.f);
        z *= z;
        acc += z * W[k * 64 + c];
    }
    t5[r * 64 + c] = acc;
    ls[tid] = acc; ls2[tid] = acc * acc;
    __syncthreads();
    if (tid < 64) {
        float s = ls[tid] + ls[tid + 64] + ls[tid + 128] + ls[tid + 192];
        float q = ls2[tid] + ls2[tid + 64] + ls2[tid + 128] + ls2[tid + 192];
        unsafeAtomicAdd(&stats5[c], s);
        unsafeAtomicAdd(&stats5[64 + c], q);
    }
}

// out = ((relu(bn(t5;g5,be5)))^4) @ W_fc3 + b
__global__ __launch_bounds__(256) void fc3_kernel(const float* __restrict__ t5,
                                                  const float* __restrict__ stats5,
                                                  const float* __restrict__ g5,
                                                  const float* __restrict__ be5,
                                                  const float* __restrict__ W,
                                                  const float* __restrict__ bias,
                                                  float* __restrict__ out) {
    __shared__ float sc[64], sh[64];
    int tid = threadIdx.x;
    if (tid < 64) {
        float m = stats5[tid] * (1.0f / BSZ);
        float var = stats5[64 + tid] * (1.0f / BSZ) - m * m;
        float s = g5[tid] * rsqrtf(var + EPS);
        sc[tid] = s; sh[tid] = be5[tid] - m * s;
    }
    __syncthreads();
    int r = blockIdx.x * 256 + tid;
    float acc = bias[0];
    const float* row = t5 + (size_t)r * 64;
#pragma unroll
    for (int k = 0; k < 64; ++k) {
        float z = fmaxf(row[k] * sc[k] + sh[k], 0.f);
        z = z * z;
        z = z * z;
        acc += z * W[k];
    }
    out[r] = acc;
}

extern "C" void kernel_launch(void* const* d_in, const int* in_sizes, int n_in,
                              void* d_out, int out_size, void* d_ws, size_t ws_size,
                              hipStream_t stream) {
    const float* x      = (const float*)d_in[0];
    const int*   masks  = (const int*)d_in[1];
    const float* gnn_x  = (const float*)d_in[2];
    const int*   ei     = (const int*)d_in[3];
    const int*   gbatch = (const int*)d_in[4];
    const float* W_gcn  = (const float*)d_in[5];
    const float* b_gcn  = (const float*)d_in[6];   // cancels in folded BN1
    const float* g1     = (const float*)d_in[7];
    const float* be1    = (const float*)d_in[8];
    const float* W_lin1 = (const float*)d_in[9];
    const float* b_lin1 = (const float*)d_in[10];
    const float* g2     = (const float*)d_in[11];
    const float* be2    = (const float*)d_in[12];
    const float* W_lin2 = (const float*)d_in[13];
    const float* b_lin2 = (const float*)d_in[14];
    const float* g3     = (const float*)d_in[15];
    const float* be3    = (const float*)d_in[16];
    const float* W_fc1  = (const float*)d_in[17];
    const float* b_fc1  = (const float*)d_in[18];
    const float* g4     = (const float*)d_in[19];
    const float* be4    = (const float*)d_in[20];
    const float* W_fc2  = (const float*)d_in[21];
    const float* b_fc2  = (const float*)d_in[22];
    const float* g5     = (const float*)d_in[23];
    const float* be5    = (const float*)d_in[24];
    const float* W_fc3  = (const float*)d_in[25];
    const float* b_fc3  = (const float*)d_in[26];
    (void)b_gcn;

    float* ws = (float*)d_ws;
    float* psum   = ws + WS_PSUM;
    float* stats1 = ws + WS_STATS1;
    float* stats2 = ws + WS_STATS2;
    float* stats4 = ws + WS_STATS4;
    float* stats5 = ws + WS_STATS5;
    float* Mbuf   = ws + WS_M;
    float* CSbuf  = ws + WS_CS;
    int*   gcur   = (int*)(ws + WS_GCUR);
    float* scale1 = ws + WS_SCALE1;
    float* shiftp = ws + WS_SHIFTP;
    int*   gstart = (int*)(ws + WS_GSTART);
    float* dis    = ws + WS_DIS;
    unsigned int* packed = (unsigned int*)(ws + WS_PACKED);
    unsigned short* xh = (unsigned short*)(ws + WS_XH);
    float* aggx   = ws + WS_AGGX;
    float* t1     = ws + WS_T1;
    float* t2     = ws + WS_T2;
    float* t4     = ws + WS_T4;
    float* t5     = ws + WS_T5;
    float* out    = (float*)d_out;

    prep_cvt_kernel<<<CVT_BLOCKS + 21, 256, 0, stream>>>(ws, gbatch, gnn_x, xh);
    bin_kernel<<<BIN_BLOCKS, 512, 0, stream>>>(ei, gcur, packed);
    degdis_kernel<<<NBUCK, 256, 0, stream>>>(packed, gcur, dis);
    gather_kernel<<<NBUCK * NWIN, 512, 0, stream>>>(xh, packed, gcur, dis, aggx);
    moment_kernel<<<NCHUNK, 256, 0, stream>>>(aggx, Mbuf, CSbuf);
    fold_kernel<<<128, 64, 0, stream>>>(Mbuf, CSbuf, W_gcn, g1, be1, scale1, shiftp);
    gemm_pool_kernel<<<N_NODES / 16, 256, 0, stream>>>(aggx, gbatch, W_gcn, scale1, shiftp, psum);
    lin1_kernel<<<256, 256, 0, stream>>>(psum, gstart, W_lin1, b_lin1, t1, stats1);
    lin2_kernel<<<256, 256, 0, stream>>>(t1, stats1, g2, be2, W_lin2, b_lin2, t2, stats2);
    fc1_kernel<<<256, 1024, 0, stream>>>(x, masks, t2, stats2, g3, be3, W_fc1, b_fc1, t4, stats4);
    fc2_kernel<<<256, 256, 0, stream>>>(t4, stats4, g4, be4, W_fc2, b_fc2, t5, stats5);
    fc3_kernel<<<4, 256, 0, stream>>>(t5, stats5, g5, be5, W_fc3, b_fc3, out);
}

// Round 10
// 242.508 us; speedup vs baseline: 3.1346x; 3.1346x over previous
//
#include <hip/hip_runtime.h>
#include <hip/hip_bf16.h>

#define N_NODES 100000
#define N_EDGES 1600000
#define N_GRAPHS 1024
#define BSZ 1024
#define EPS 1e-5f

#define NBUCK 256
#define BUCKW 391          // ceil(100000/256)
#define BCAP  8192         // static per-bucket edge capacity (mean 6250, sd 79)
#define SRC_MASK 0x1FFFF   // 17 bits for src (<131072)
#define BIN_CHUNK 4096
#define BIN_BLOCKS 391     // ceil(1600000/4096)
#define NCHUNK 512         // moment row-chunks
#define CHUNK_ROWS 196     // 512*196 = 100352 >= 100000
#define CVT_BLOCKS 6250    // 100000*64/4/256

// ---------------- workspace layout (4-byte units) ----------------
// zeroed-every-call region:
#define WS_PSUM    0          // 1024*128 pooled sums
#define WS_STATS1  131072     // 128
#define WS_STATS2  131200     // 128
#define WS_STATS4  131328     // 512
#define WS_STATS5  131840     // 128
#define WS_M       131968     // 4096 (aggx^T aggx)
#define WS_CS      136064     // 64 (aggx column sums)
#define WS_ZTOTAL  136128
// written-before-read region:
#define WS_GCUR    136128     // 256 int (init to b*BCAP by prep)
#define WS_SCALE1  136384     // 128
#define WS_SHIFTP  136512     // 128
#define WS_GSTART  136640     // 1025 int (pad to 137668)
#define WS_DIS     137668     // 100000 float -> 237668
#define WS_ROWPTR  237668     // 100000 int -> 337668
#define WS_ROWLEN  337668     // 100000 int -> 437668
#define WS_PACKED  437668     // 256*8192 u32 -> 2534820
#define WS_CSRC    2534820    // 256*8192 int -> 4631972
#define WS_XH      4631972    // 100000*64 ushort = 3200000 words -> 7831972
#define WS_AGGX    7831972    // 100000*64 -> 14231972
#define WS_T1      14231972   // 1024*64 -> 14297508
#define WS_T2      14297508   // 1024*64 -> 14363044
#define WS_T4      14363044   // 1024*256 -> 14625188
#define WS_T5      14625188   // 1024*64 -> 14690724
// total = 14690724 words = ~58.8 MB

__device__ inline unsigned short f2bf(float f) {
    unsigned int u = __float_as_uint(f);
    return (unsigned short)((u + 0x7FFFu + ((u >> 16) & 1u)) >> 16);
}

// blocks 0..6249: fp32->bf16 convert; 6250..6265: zero; 6266: gcur; 6267..6270: graph bounds
__global__ __launch_bounds__(256) void prep_cvt_kernel(float* __restrict__ ws,
                                                       const int* __restrict__ gbatch,
                                                       const float* __restrict__ x,
                                                       unsigned short* __restrict__ xh) {
    int b = blockIdx.x, tid = threadIdx.x;
    if (b < CVT_BLOCKS) {
        int i = b * 256 + tid;
        float4 f = ((const float4*)x)[i];
        ushort4 h;
        h.x = f2bf(f.x); h.y = f2bf(f.y); h.z = f2bf(f.z); h.w = f2bf(f.w);
        ((ushort4*)xh)[i] = h;
    } else if (b < CVT_BLOCKS + 16) {
        for (int i = (b - CVT_BLOCKS) * 256 + tid; i < WS_ZTOTAL; i += 16 * 256) ws[i] = 0.0f;
    } else if (b == CVT_BLOCKS + 16) {
        ((int*)(ws + WS_GCUR))[tid] = tid * BCAP;
    } else {
        int g = (b - (CVT_BLOCKS + 17)) * 256 + tid;
        int lo = 0, hi = N_NODES;
        while (lo < hi) {
            int mid = (lo + hi) >> 1;
            if (gbatch[mid] < g) lo = mid + 1; else hi = mid;
        }
        int* gstart = (int*)(ws + WS_GSTART);
        gstart[g] = lo;
        if (g == 0) gstart[N_GRAPHS] = N_NODES;
    }
}

// bin edges into 256 coarse dst-buckets (static BCAP stride) with LDS staging
__global__ __launch_bounds__(512) void bin_kernel(const int* __restrict__ ei,
                                                  int* __restrict__ gcursor,
                                                  unsigned int* __restrict__ packed) {
    __shared__ unsigned int stage[BIN_CHUNK];   // 16KB
    __shared__ int lh[NBUCK], lbase[NBUCK], lcur[NBUCK], gb[NBUCK];
    const int* src = ei;
    const int* dst = ei + N_EDGES;
    int tid = threadIdx.x;
    int base = blockIdx.x * BIN_CHUNK;
    int n = min(BIN_CHUNK, N_EDGES - base);
    if (tid < NBUCK) lh[tid] = 0;
    __syncthreads();
    for (int i = tid; i < n; i += 512)
        atomicAdd(&lh[dst[base + i] / BUCKW], 1);
    __syncthreads();
    if (tid < NBUCK) lbase[tid] = lh[tid];
    __syncthreads();
    for (int off = 1; off < NBUCK; off <<= 1) {
        int t = (tid < NBUCK && tid >= off) ? lbase[tid - off] : 0;
        __syncthreads();
        if (tid < NBUCK) lbase[tid] += t;
        __syncthreads();
    }
    if (tid < NBUCK) {
        int excl = lbase[tid] - lh[tid];
        lbase[tid] = excl;
        lcur[tid] = excl;
        gb[tid] = atomicAdd(&gcursor[tid], lh[tid]);
    }
    __syncthreads();
    for (int i = tid; i < n; i += 512) {
        int d = dst[base + i];
        int s = src[base + i];
        int bk = d / BUCKW;
        int dl = d - bk * BUCKW;
        int slot = atomicAdd(&lcur[bk], 1);
        stage[slot] = ((unsigned int)dl << 17) | (unsigned int)s;
    }
    __syncthreads();
    int wid = tid >> 6, lane = tid & 63;
    for (int bk = wid; bk < NBUCK; bk += 8) {
        int lo = lbase[bk], go = gb[bk];
        int len = min(lh[bk], (bk + 1) * BCAP - go);  // overflow clamp (never expected)
        for (int j = lane; j < len; j += 64)
            packed[go + j] = stage[lo + j];
    }
}

// per-bucket: exact CSR (sorted in LDS, coalesced write) + rowptr/rowlen + dis
__global__ __launch_bounds__(512) void csr_build_kernel(const unsigned int* __restrict__ packed,
                                                        const int* __restrict__ gcur,
                                                        int* __restrict__ rowptr,
                                                        int* __restrict__ rowlen,
                                                        int* __restrict__ csrc,
                                                        float* __restrict__ dis) {
    __shared__ int dcnt[BUCKW];
    __shared__ int lcur[BUCKW];
    __shared__ int stage[BCAP];       // 32KB
    int b = blockIdx.x, tid = threadIdx.x;
    int e0 = b * BCAP;
    int ecnt = min(gcur[b] - e0, BCAP);
    int nbase = b * BUCKW;
    int nmax = min(BUCKW, N_NODES - nbase);
    for (int i = tid; i < BUCKW; i += 512) dcnt[i] = 0;
    __syncthreads();
    for (int i = tid; i < ecnt; i += 512)
        atomicAdd(&dcnt[packed[e0 + i] >> 17], 1);
    __syncthreads();
    for (int i = tid; i < nmax; i += 512) {
        dis[nbase + i] = rsqrtf((float)dcnt[i] + 1.0f);
        rowlen[nbase + i] = dcnt[i];
    }
    __syncthreads();
    if (tid < 64) {
        int lane = tid;
        int run = 0;
        for (int c = 0; c < BUCKW; c += 64) {
            int idx = c + lane;
            int v = (idx < BUCKW) ? dcnt[idx] : 0;
            int inc = v;
#pragma unroll
            for (int off = 1; off < 64; off <<= 1) {
                int t = __shfl_up(inc, off);
                if (lane >= off) inc += t;
            }
            if (idx < BUCKW) {
                int excl = run + inc - v;
                dcnt[idx] = excl;
                lcur[idx] = excl;
            }
            run += __shfl(inc, 63);
        }
    }
    __syncthreads();
    for (int i = tid; i < nmax; i += 512)
        rowptr[nbase + i] = e0 + dcnt[i];
    for (int i = tid; i < ecnt; i += 512) {
        unsigned int r = packed[e0 + i];
        int slot = atomicAdd(&lcur[r >> 17], 1);
        stage[slot] = (int)(r & SRC_MASK);
    }
    __syncthreads();
    for (int i = tid; i < ecnt; i += 512) csrc[e0 + i] = stage[i];
}

// aggx[n] = xh[n]*dis[n]^2 + sum_{s in in(n)} xh[s]*dis[s]*dis[n]
// one wave per node, 8-deep pipelined gather; all table reads bf16
__global__ __launch_bounds__(256) void gather_kernel(const unsigned short* __restrict__ xh,
                                                     const int* __restrict__ rowptr,
                                                     const int* __restrict__ rowlen,
                                                     const int* __restrict__ csrc,
                                                     const float* __restrict__ dis,
                                                     float* __restrict__ aggx) {
    int wid = (blockIdx.x * 256 + threadIdx.x) >> 6;
    int lane = threadIdx.x & 63;
    if (wid >= N_NODES) return;
    int start = rowptr[wid];
    int len = rowlen[wid];
    float dd = dis[wid];
    float self = __uint_as_float((unsigned int)xh[(size_t)wid * 64 + lane] << 16);
    float acc = self * dd * dd;
    for (int j0 = 0; j0 < len; j0 += 64) {
        int cnt = min(64, len - j0);
        int sv = 0;
        float wv = 0.f;
        if (lane < cnt) {
            sv = csrc[start + j0 + lane];
            wv = dis[sv] * dd;
        }
        int iters = (cnt + 7) & ~7;
        for (int k = 0; k < iters; k += 8) {
            int s[8]; float w[8], v[8];
#pragma unroll
            for (int u = 0; u < 8; ++u) {
                s[u] = __shfl(sv, k + u);
                w[u] = __shfl(wv, k + u);
            }
#pragma unroll
            for (int u = 0; u < 8; ++u)
                v[u] = __uint_as_float((unsigned int)xh[(size_t)s[u] * 64 + lane] << 16);
#pragma unroll
            for (int u = 0; u < 8; ++u) acc = fmaf(v[u], w[u], acc);
        }
    }
    aggx[(size_t)wid * 64 + lane] = acc;
}

// partial second moments, atomically accumulated into M[64][64] and CS[64]
__global__ __launch_bounds__(256) void moment_kernel(const float* __restrict__ aggx,
                                                     float* __restrict__ M,
                                                     float* __restrict__ CS) {
    __shared__ float rows[8 * 64];
    int c = blockIdx.x, tid = threadIdx.x;
    int r0 = c * CHUNK_ROWS;
    int r1 = min(r0 + CHUNK_ROWS, N_NODES);
    int i0 = (tid >> 6) * 16;
    int j = tid & 63;
    float acc[16] = {};
    float cs = 0.f;
    for (int it = 0; it < (CHUNK_ROWS + 7) / 8; ++it) {
        int sid = tid * 2;
        int grow = r0 + it * 8 + (sid >> 6);
        float2 v = {0.f, 0.f};
        if (grow < r1) v = *(const float2*)(aggx + (size_t)(r0 + it * 8) * 64 + sid);
        __syncthreads();
        *(float2*)(rows + sid) = v;
        __syncthreads();
#pragma unroll
        for (int rr = 0; rr < 8; ++rr) {
            float bj = rows[rr * 64 + j];
            float4 a0 = *(const float4*)(rows + rr * 64 + i0);
            float4 a1 = *(const float4*)(rows + rr * 64 + i0 + 4);
            float4 a2 = *(const float4*)(rows + rr * 64 + i0 + 8);
            float4 a3 = *(const float4*)(rows + rr * 64 + i0 + 12);
            acc[0]  += a0.x * bj; acc[1]  += a0.y * bj; acc[2]  += a0.z * bj; acc[3]  += a0.w * bj;
            acc[4]  += a1.x * bj; acc[5]  += a1.y * bj; acc[6]  += a1.z * bj; acc[7]  += a1.w * bj;
            acc[8]  += a2.x * bj; acc[9]  += a2.y * bj; acc[10] += a2.z * bj; acc[11] += a2.w * bj;
            acc[12] += a3.x * bj; acc[13] += a3.y * bj; acc[14] += a3.z * bj; acc[15] += a3.w * bj;
        }
        if (tid < 64) {
#pragma unroll
            for (int rr = 0; rr < 8; ++rr) cs += rows[rr * 64 + tid];
        }
    }
#pragma unroll
    for (int m = 0; m < 16; ++m)
        unsafeAtomicAdd(&M[(i0 + m) * 64 + j], acc[m]);
    if (tid < 64) unsafeAtomicAdd(&CS[tid], cs);
}

// folded BN1 scale/shift: one block per output column j, 64 threads, no per-thread arrays
// var_j = (w_j^T M w_j)/N - my_j^2 ; my_j = (CS . w_j)/N   (b_gcn cancels)
__global__ __launch_bounds__(64) void fold_kernel(const float* __restrict__ M,
                                                  const float* __restrict__ CS,
                                                  const float* __restrict__ W,
                                                  const float* __restrict__ g1,
                                                  const float* __restrict__ be1,
                                                  float* __restrict__ scale1,
                                                  float* __restrict__ shiftp) {
    __shared__ float wcol[64];
    int j = blockIdx.x;
    int lane = threadIdx.x;
    wcol[lane] = W[lane * 128 + j];
    __syncthreads();
    float wl = wcol[lane];
    float t = 0.f;
    const float* Mrow = M + lane * 64;
#pragma unroll 16
    for (int k = 0; k < 64; ++k) t += Mrow[k] * wcol[k];
    float part = t * wl;
    float csp = CS[lane] * wl;
#pragma unroll
    for (int off = 32; off; off >>= 1) {
        part += __shfl_xor(part, off);
        csp  += __shfl_xor(csp, off);
    }
    if (lane == 0) {
        float Ey2 = part * (1.0f / N_NODES);
        float my = csp * (1.0f / N_NODES);
        float var = Ey2 - my * my;
        float sc = g1[j] * rsqrtf(var + EPS);
        scale1[j] = sc;
        shiftp[j] = be1[j] - my * sc;
    }
}

// fused: y = aggx_tile @ W, z = relu(y*sc+sh), segment-run atomicAdd into psum[g][c]
// (gnn_batch sorted -> a 16-row tile spans 1-3 graphs)
__global__ __launch_bounds__(256) void gemm_pool_kernel(const float* __restrict__ aggx,
                                                        const int* __restrict__ gbatch,
                                                        const float* __restrict__ W,
                                                        const float* __restrict__ scale1,
                                                        const float* __restrict__ shiftp,
                                                        float* __restrict__ psum) {
    __shared__ float Ws[64 * 128];   // 32KB
    __shared__ float As[16 * 64];    // 4KB
    __shared__ float Zs[16 * 128];   // 8KB
    __shared__ int gid[16];
    int tid = threadIdx.x;
    const float4* W4 = (const float4*)W;
    float4* Ws4 = (float4*)Ws;
#pragma unroll
    for (int i = 0; i < 8; ++i) Ws4[tid + i * 256] = W4[tid + i * 256];
    int row0 = blockIdx.x * 16;
    ((float4*)As)[tid] = ((const float4*)(aggx + (size_t)row0 * 64))[tid];
    if (tid < 16) gid[tid] = gbatch[row0 + tid];
    __syncthreads();
    int tx = tid & 31;
    int ty = tid >> 5;
    int r0 = ty * 2;
    float4 sc4 = ((const float4*)scale1)[tx];
    float4 sh4 = ((const float4*)shiftp)[tx];
    float acc[2][4] = {};
#pragma unroll
    for (int k = 0; k < 64; ++k) {
        float a0 = As[r0 * 64 + k];
        float a1 = As[(r0 + 1) * 64 + k];
        float4 w = Ws4[k * 32 + tx];
        acc[0][0] += a0 * w.x; acc[0][1] += a0 * w.y; acc[0][2] += a0 * w.z; acc[0][3] += a0 * w.w;
        acc[1][0] += a1 * w.x; acc[1][1] += a1 * w.y; acc[1][2] += a1 * w.z; acc[1][3] += a1 * w.w;
    }
#pragma unroll
    for (int rr = 0; rr < 2; ++rr) {
        float4 z;
        z.x = fmaxf(acc[rr][0] * sc4.x + sh4.x, 0.f);
        z.y = fmaxf(acc[rr][1] * sc4.y + sh4.y, 0.f);
        z.z = fmaxf(acc[rr][2] * sc4.z + sh4.z, 0.f);
        z.w = fmaxf(acc[rr][3] * sc4.w + sh4.w, 0.f);
        ((float4*)(Zs + (r0 + rr) * 128))[tx] = z;
    }
    __syncthreads();
    if (tid < 128) {
        int c = tid;
        float a = 0.f;
        int g = gid[0];
#pragma unroll
        for (int i = 0; i < 16; ++i) {
            int gi = gid[i];
            if (gi != g) {
                unsafeAtomicAdd(&psum[(size_t)g * 128 + c], a);
                a = 0.f;
                g = gi;
            }
            a += Zs[i * 128 + c];
        }
        unsafeAtomicAdd(&psum[(size_t)g * 128 + c], a);
    }
}

// t1 = (psum/cnt) @ W_lin1 + b ; stats1 += (sum, sumsq)
__global__ __launch_bounds__(256) void lin1_kernel(const float* __restrict__ psum,
                                                   const int* __restrict__ gstart,
                                                   const float* __restrict__ W,
                                                   const float* __restrict__ bias,
                                                   float* __restrict__ t1,
                                                   float* __restrict__ stats1) {
    __shared__ float ls[256], ls2[256];
    int tid = threadIdx.x;
    int r = blockIdx.x * 4 + (tid >> 6);
    int c = tid & 63;
    float invc = 1.0f / fmaxf((float)(gstart[r + 1] - gstart[r]), 1.0f);
    float acc = 0.f;
    const float* srow = psum + (size_t)r * 128;
#pragma unroll 8
    for (int k = 0; k < 128; ++k)
        acc += srow[k] * W[k * 64 + c];
    acc = bias[c] + acc * invc;
    t1[r * 64 + c] = acc;
    ls[tid] = acc; ls2[tid] = acc * acc;
    __syncthreads();
    if (tid < 64) {
        float s = ls[tid] + ls[tid + 64] + ls[tid + 128] + ls[tid + 192];
        float q = ls2[tid] + ls2[tid + 64] + ls2[tid + 128] + ls2[tid + 192];
        unsafeAtomicAdd(&stats1[c], s);
        unsafeAtomicAdd(&stats1[64 + c], q);
    }
}

// t2 = relu(bn(t1; g2,be2)) @ W_lin2 + b ; stats2
__global__ __launch_bounds__(256) void lin2_kernel(const float* __restrict__ t1,
                                                   const float* __restrict__ stats1,
                                                   const float* __restrict__ g,
                                                   const float* __restrict__ be,
                                                   const float* __restrict__ W,
                                                   const float* __restrict__ bias,
                                                   float* __restrict__ t2,
                                                   float* __restrict__ stats2) {
    __shared__ float sc[64], sh[64];
    __shared__ float ls[256], ls2[256];
    int tid = threadIdx.x;
    if (tid < 64) {
        float m = stats1[tid] * (1.0f / BSZ);
        float var = stats1[64 + tid] * (1.0f / BSZ) - m * m;
        float s = g[tid] * rsqrtf(var + EPS);
        sc[tid] = s; sh[tid] = be[tid] - m * s;
    }
    __syncthreads();
    int r = blockIdx.x * 4 + (tid >> 6);
    int c = tid & 63;
    float acc = bias[c];
    const float* row = t1 + (size_t)r * 64;
#pragma unroll 8
    for (int k = 0; k < 64; ++k) {
        float z = fmaxf(row[k] * sc[k] + sh[k], 0.f);
        acc += z * W[k * 64 + c];
    }
    t2[r * 64 + c] = acc;
    ls[tid] = acc; ls2[tid] = acc * acc;
    __syncthreads();
    if (tid < 64) {
        float s = ls[tid] + ls[tid + 64] + ls[tid + 128] + ls[tid + 192];
        float q = ls2[tid] + ls2[tid + 64] + ls2[tid + 128] + ls2[tid + 192];
        unsafeAtomicAdd(&stats2[c], s);
        unsafeAtomicAdd(&stats2[64 + c], q);
    }
}

// t4 = concat(x, bn(t2;g3,be3)[masks]) @ W_fc1 + b ; stats4
__global__ __launch_bounds__(1024) void fc1_kernel(const float* __restrict__ x,
                                                   const int* __restrict__ masks,
                                                   const float* __restrict__ t2,
                                                   const float* __restrict__ stats2,
                                                   const float* __restrict__ g3,
                                                   const float* __restrict__ be3,
                                                   const float* __restrict__ W,
                                                   const float* __restrict__ bias,
                                                   float* __restrict__ t4,
                                                   float* __restrict__ stats4) {
    __shared__ float sc[64], sh[64];
    __shared__ float cat[4][128];
    __shared__ float ls[1024], ls2[1024];
    int tid = threadIdx.x;
    if (tid < 64) {
        float m = stats2[tid] * (1.0f / BSZ);
        float var = stats2[64 + tid] * (1.0f / BSZ) - m * m;
        float s = g3[tid] * rsqrtf(var + EPS);
        sc[tid] = s; sh[tid] = be3[tid] - m * s;
    }
    __syncthreads();
    int r0 = blockIdx.x * 4;
    if (tid < 512) {
        int i = tid >> 7;
        int k = tid & 127;
        int r = r0 + i;
        float v;
        if (k < 64) {
            v = x[r * 64 + k];
        } else {
            int mrow = masks[r];
            int kk = k - 64;
            v = t2[mrow * 64 + kk] * sc[kk] + sh[kk];
        }
        cat[i][k] = v;
    }
    __syncthreads();
    int i = tid >> 8;
    int c = tid & 255;
    float acc = bias[c];
#pragma unroll 8
    for (int k = 0; k < 128; ++k)
        acc += cat[i][k] * W[k * 256 + c];
    t4[(size_t)(r0 + i) * 256 + c] = acc;
    ls[tid] = acc; ls2[tid] = acc * acc;
    __syncthreads();
    if (tid < 256) {
        float s = ls[tid] + ls[tid + 256] + ls[tid + 512] + ls[tid + 768];
        float q = ls2[tid] + ls2[tid + 256] + ls2[tid + 512] + ls2[tid + 768];
        unsafeAtomicAdd(&stats4[c], s);
        unsafeAtomicAdd(&stats4[256 + c], q);
    }
}

// t5 = (relu(bn(t4;g4,be4))^2) @ W_fc2 + b ; stats5
__global__ __launch_bounds__(256) void fc2_kernel(const float* __restrict__ t4,
                                                  const float* __restrict__ stats4,
                                                  const float* __restrict__ g4,
                                                  const float* __restrict__ be4,
                                                  const float* __restrict__ W,
                                                  const float* __restrict__ bias,
                                                  float* __restrict__ t5,
                                                  float* __restrict__ stats5) {
    __shared__ float sc[256], sh[256];
    __shared__ float ls[256], ls2[256];
    int tid = threadIdx.x;
    {
        float m = stats4[tid] * (1.0f / BSZ);
        float var = stats4[256 + tid] * (1.0f / BSZ) - m * m;
        float s = g4[tid] * rsqrtf(var + EPS);
        sc[tid] = s; sh[tid] = be4[tid] - m * s;
    }
    __syncthreads();
    int r = blockIdx.x * 4 + (tid >> 6);
    int c = tid & 63;
    float acc = bias[c];
    const float* row = t4 + (size_t)r * 256;
#pragma unroll 8
    for (int k = 0; k < 256; ++k) {
        float z = fmaxf(row[k] * sc[k] + sh[k], 0.f);
        z *= z;
        acc += z * W[k * 64 + c];
    }
    t5[r * 64 + c] = acc;
    ls[tid] = acc; ls2[tid] = acc * acc;
    __syncthreads();
    if (tid < 64) {
        float s = ls[tid] + ls[tid + 64] + ls[tid + 128] + ls[tid + 192];
        float q = ls2[tid] + ls2[tid + 64] + ls2[tid + 128] + ls2[tid + 192];
        unsafeAtomicAdd(&stats5[c], s);
        unsafeAtomicAdd(&stats5[64 + c], q);
    }
}

// out = ((relu(bn(t5;g5,be5)))^4) @ W_fc3 + b
__global__ __launch_bounds__(256) void fc3_kernel(const float* __restrict__ t5,
                                                  const float* __restrict__ stats5,
                                                  const float* __restrict__ g5,
                                                  const float* __restrict__ be5,
                                                  const float* __restrict__ W,
                                                  const float* __restrict__ bias,
                                                  float* __restrict__ out) {
    __shared__ float sc[64], sh[64];
    int tid = threadIdx.x;
    if (tid < 64) {
        float m = stats5[tid] * (1.0f / BSZ);
        float var = stats5[64 + tid] * (1.0f / BSZ) - m * m;
        float s = g5[tid] * rsqrtf(var + EPS);
        sc[tid] = s; sh[tid] = be5[tid] - m * s;
    }
    __syncthreads();
    int r = blockIdx.x * 256 + tid;
    float acc = bias[0];
    const float* row = t5 + (size_t)r * 64;
#pragma unroll
    for (int k = 0; k < 64; ++k) {
        float z = fmaxf(row[k] * sc[k] + sh[k], 0.f);
        z = z * z;
        z = z * z;
        acc += z * W[k];
    }
    out[r] = acc;
}

extern "C" void kernel_launch(void* const* d_in, const int* in_sizes, int n_in,
                              void* d_out, int out_size, void* d_ws, size_t ws_size,
                              hipStream_t stream) {
    const float* x      = (const float*)d_in[0];
    const int*   masks  = (const int*)d_in[1];
    const float* gnn_x  = (const float*)d_in[2];
    const int*   ei     = (const int*)d_in[3];
    const int*   gbatch = (const int*)d_in[4];
    const float* W_gcn  = (const float*)d_in[5];
    const float* b_gcn  = (const float*)d_in[6];   // cancels in folded BN1
    const float* g1     = (const float*)d_in[7];
    const float* be1    = (const float*)d_in[8];
    const float* W_lin1 = (const float*)d_in[9];
    const float* b_lin1 = (const float*)d_in[10];
    const float* g2     = (const float*)d_in[11];
    const float* be2    = (const float*)d_in[12];
    const float* W_lin2 = (const float*)d_in[13];
    const float* b_lin2 = (const float*)d_in[14];
    const float* g3     = (const float*)d_in[15];
    const float* be3    = (const float*)d_in[16];
    const float* W_fc1  = (const float*)d_in[17];
    const float* b_fc1  = (const float*)d_in[18];
    const float* g4     = (const float*)d_in[19];
    const float* be4    = (const float*)d_in[20];
    const float* W_fc2  = (const float*)d_in[21];
    const float* b_fc2  = (const float*)d_in[22];
    const float* g5     = (const float*)d_in[23];
    const float* be5    = (const float*)d_in[24];
    const float* W_fc3  = (const float*)d_in[25];
    const float* b_fc3  = (const float*)d_in[26];
    (void)b_gcn;

    float* ws = (float*)d_ws;
    float* psum   = ws + WS_PSUM;
    float* stats1 = ws + WS_STATS1;
    float* stats2 = ws + WS_STATS2;
    float* stats4 = ws + WS_STATS4;
    float* stats5 = ws + WS_STATS5;
    float* Mbuf   = ws + WS_M;
    float* CSbuf  = ws + WS_CS;
    int*   gcur   = (int*)(ws + WS_GCUR);
    float* scale1 = ws + WS_SCALE1;
    float* shiftp = ws + WS_SHIFTP;
    int*   gstart = (int*)(ws + WS_GSTART);
    float* dis    = ws + WS_DIS;
    int*   rowptr = (int*)(ws + WS_ROWPTR);
    int*   rowlen = (int*)(ws + WS_ROWLEN);
    unsigned int* packed = (unsigned int*)(ws + WS_PACKED);
    int*   csrc   = (int*)(ws + WS_CSRC);
    unsigned short* xh = (unsigned short*)(ws + WS_XH);
    float* aggx   = ws + WS_AGGX;
    float* t1     = ws + WS_T1;
    float* t2     = ws + WS_T2;
    float* t4     = ws + WS_T4;
    float* t5     = ws + WS_T5;
    float* out    = (float*)d_out;

    prep_cvt_kernel<<<CVT_BLOCKS + 21, 256, 0, stream>>>(ws, gbatch, gnn_x, xh);
    bin_kernel<<<BIN_BLOCKS, 512, 0, stream>>>(ei, gcur, packed);
    csr_build_kernel<<<NBUCK, 512, 0, stream>>>(packed, gcur, rowptr, rowlen, csrc, dis);
    gather_kernel<<<(N_NODES * 64 + 255) / 256, 256, 0, stream>>>(xh, rowptr, rowlen, csrc, dis, aggx);
    moment_kernel<<<NCHUNK, 256, 0, stream>>>(aggx, Mbuf, CSbuf);
    fold_kernel<<<128, 64, 0, stream>>>(Mbuf, CSbuf, W_gcn, g1, be1, scale1, shiftp);
    gemm_pool_kernel<<<N_NODES / 16, 256, 0, stream>>>(aggx, gbatch, W_gcn, scale1, shiftp, psum);
    lin1_kernel<<<256, 256, 0, stream>>>(psum, gstart, W_lin1, b_lin1, t1, stats1);
    lin2_kernel<<<256, 256, 0, stream>>>(t1, stats1, g2, be2, W_lin2, b_lin2, t2, stats2);
    fc1_kernel<<<256, 1024, 0, stream>>>(x, masks, t2, stats2, g3, be3, W_fc1, b_fc1, t4, stats4);
    fc2_kernel<<<256, 256, 0, stream>>>(t4, stats4, g4, be4, W_fc2, b_fc2, t5, stats5);
    fc3_kernel<<<4, 256, 0, stream>>>(t5, stats5, g5, be5, W_fc3, b_fc3, out);
}

// Round 11
// 237.158 us; speedup vs baseline: 3.2053x; 1.0226x over previous
//
#include <hip/hip_runtime.h>
#include <hip/hip_bf16.h>

#define N_NODES 100000
#define N_EDGES 1600000
#define N_GRAPHS 1024
#define BSZ 1024
#define EPS 1e-5f

#define NBUCK 256
#define BUCKW 391          // ceil(100000/256)
#define BCAP  8192         // static per-bucket edge capacity (mean 6250, sd 79)
#define SRC_MASK 0x1FFFF   // 17 bits for src (<131072)
#define BIN_CHUNK 4096
#define BIN_BLOCKS 391     // ceil(1600000/4096)
#define NCHUNK 512         // moment row-chunks
#define CHUNK_ROWS 196     // 512*196 = 100352 >= 100000
#define CVT_BLOCKS 6250    // 100000*64/4/256

// ---------------- workspace layout (4-byte units) ----------------
// zeroed-every-call region:
#define WS_PSUM    0          // 1024*128 pooled sums
#define WS_STATS1  131072     // 128
#define WS_STATS2  131200     // 128
#define WS_STATS4  131328     // 512
#define WS_STATS5  131840     // 128
#define WS_M       131968     // 4096 (aggx^T aggx)
#define WS_CS      136064     // 64 (aggx column sums)
#define WS_ZTOTAL  136128
// written-before-read region:
#define WS_GCUR    136128     // 256 int (init to b*BCAP by prep)
#define WS_SCALE1  136384     // 128
#define WS_SHIFTP  136512     // 128
#define WS_GSTART  136640     // 1025 int (pad to 137668)
#define WS_DIS     137668     // 100000 float -> 237668
#define WS_ROWPTR  237668     // 100000 int -> 337668
#define WS_ROWLEN  337668     // 100000 int -> 437668
#define WS_PACKED  437668     // 256*8192 u32 -> 2534820
#define WS_CSRC    2534820    // 256*8192 int -> 4631972
#define WS_XH      4631972    // 100000*64 ushort = 3200000 words -> 7831972
#define WS_AGGX    7831972    // 100000*64 ushort = 3200000 words -> 11031972
#define WS_T1      11031972   // 1024*64 -> 11097508
#define WS_T2      11097508   // 1024*64 -> 11163044
#define WS_T4      11163044   // 1024*256 -> 11425188
#define WS_T5      11425188   // 1024*64 -> 11490724
// total = 11490724 words = ~46 MB

__device__ inline unsigned short f2bf(float f) {
    unsigned int u = __float_as_uint(f);
    return (unsigned short)((u + 0x7FFFu + ((u >> 16) & 1u)) >> 16);
}
__device__ inline float bf2f(unsigned short h) {
    return __uint_as_float((unsigned int)h << 16);
}

// blocks 0..6249: fp32->bf16 convert; 6250..6265: zero; 6266: gcur; 6267..6270: graph bounds
__global__ __launch_bounds__(256) void prep_cvt_kernel(float* __restrict__ ws,
                                                       const int* __restrict__ gbatch,
                                                       const float* __restrict__ x,
                                                       unsigned short* __restrict__ xh) {
    int b = blockIdx.x, tid = threadIdx.x;
    if (b < CVT_BLOCKS) {
        int i = b * 256 + tid;
        float4 f = ((const float4*)x)[i];
        ushort4 h;
        h.x = f2bf(f.x); h.y = f2bf(f.y); h.z = f2bf(f.z); h.w = f2bf(f.w);
        ((ushort4*)xh)[i] = h;
    } else if (b < CVT_BLOCKS + 16) {
        for (int i = (b - CVT_BLOCKS) * 256 + tid; i < WS_ZTOTAL; i += 16 * 256) ws[i] = 0.0f;
    } else if (b == CVT_BLOCKS + 16) {
        ((int*)(ws + WS_GCUR))[tid] = tid * BCAP;
    } else {
        int g = (b - (CVT_BLOCKS + 17)) * 256 + tid;
        int lo = 0, hi = N_NODES;
        while (lo < hi) {
            int mid = (lo + hi) >> 1;
            if (gbatch[mid] < g) lo = mid + 1; else hi = mid;
        }
        int* gstart = (int*)(ws + WS_GSTART);
        gstart[g] = lo;
        if (g == 0) gstart[N_GRAPHS] = N_NODES;
    }
}

// bin edges into 256 coarse dst-buckets (static BCAP stride) with LDS staging
__global__ __launch_bounds__(512) void bin_kernel(const int* __restrict__ ei,
                                                  int* __restrict__ gcursor,
                                                  unsigned int* __restrict__ packed) {
    __shared__ unsigned int stage[BIN_CHUNK];   // 16KB
    __shared__ int lh[NBUCK], lbase[NBUCK], lcur[NBUCK], gb[NBUCK];
    const int* src = ei;
    const int* dst = ei + N_EDGES;
    int tid = threadIdx.x;
    int base = blockIdx.x * BIN_CHUNK;
    int n = min(BIN_CHUNK, N_EDGES - base);
    if (tid < NBUCK) lh[tid] = 0;
    __syncthreads();
    for (int i = tid; i < n; i += 512)
        atomicAdd(&lh[dst[base + i] / BUCKW], 1);
    __syncthreads();
    if (tid < NBUCK) lbase[tid] = lh[tid];
    __syncthreads();
    for (int off = 1; off < NBUCK; off <<= 1) {
        int t = (tid < NBUCK && tid >= off) ? lbase[tid - off] : 0;
        __syncthreads();
        if (tid < NBUCK) lbase[tid] += t;
        __syncthreads();
    }
    if (tid < NBUCK) {
        int excl = lbase[tid] - lh[tid];
        lbase[tid] = excl;
        lcur[tid] = excl;
        gb[tid] = atomicAdd(&gcursor[tid], lh[tid]);
    }
    __syncthreads();
    for (int i = tid; i < n; i += 512) {
        int d = dst[base + i];
        int s = src[base + i];
        int bk = d / BUCKW;
        int dl = d - bk * BUCKW;
        int slot = atomicAdd(&lcur[bk], 1);
        stage[slot] = ((unsigned int)dl << 17) | (unsigned int)s;
    }
    __syncthreads();
    int wid = tid >> 6, lane = tid & 63;
    for (int bk = wid; bk < NBUCK; bk += 8) {
        int lo = lbase[bk], go = gb[bk];
        int len = min(lh[bk], (bk + 1) * BCAP - go);  // overflow clamp (never expected)
        for (int j = lane; j < len; j += 64)
            packed[go + j] = stage[lo + j];
    }
}

// per-bucket: exact CSR via single global read (pk staged in LDS) + rowptr/rowlen + dis
__global__ __launch_bounds__(512) void csr_build_kernel(const unsigned int* __restrict__ packed,
                                                        const int* __restrict__ gcur,
                                                        int* __restrict__ rowptr,
                                                        int* __restrict__ rowlen,
                                                        int* __restrict__ csrc,
                                                        float* __restrict__ dis) {
    __shared__ unsigned int pk[BCAP]; // 32KB  (single global read of packed)
    __shared__ int dcnt[BUCKW];
    __shared__ int lcur[BUCKW];
    __shared__ int stage[BCAP];       // 32KB
    int b = blockIdx.x, tid = threadIdx.x;
    int e0 = b * BCAP;
    int ecnt = min(gcur[b] - e0, BCAP);
    int nbase = b * BUCKW;
    int nmax = min(BUCKW, N_NODES - nbase);
    for (int i = tid; i < BUCKW; i += 512) dcnt[i] = 0;
    __syncthreads();
    for (int i = tid; i < ecnt; i += 512) {
        unsigned int r = packed[e0 + i];
        pk[i] = r;
        atomicAdd(&dcnt[r >> 17], 1);
    }
    __syncthreads();
    for (int i = tid; i < nmax; i += 512) {
        dis[nbase + i] = rsqrtf((float)dcnt[i] + 1.0f);
        rowlen[nbase + i] = dcnt[i];
    }
    __syncthreads();
    if (tid < 64) {
        int lane = tid;
        int run = 0;
        for (int c = 0; c < BUCKW; c += 64) {
            int idx = c + lane;
            int v = (idx < BUCKW) ? dcnt[idx] : 0;
            int inc = v;
#pragma unroll
            for (int off = 1; off < 64; off <<= 1) {
                int t = __shfl_up(inc, off);
                if (lane >= off) inc += t;
            }
            if (idx < BUCKW) {
                int excl = run + inc - v;
                dcnt[idx] = excl;
                lcur[idx] = excl;
            }
            run += __shfl(inc, 63);
        }
    }
    __syncthreads();
    for (int i = tid; i < nmax; i += 512)
        rowptr[nbase + i] = e0 + dcnt[i];
    for (int i = tid; i < ecnt; i += 512) {
        unsigned int r = pk[i];
        int slot = atomicAdd(&lcur[r >> 17], 1);
        stage[slot] = (int)(r & SRC_MASK);
    }
    __syncthreads();
    for (int i = tid; i < ecnt; i += 512) csrc[e0 + i] = stage[i];
}

// aggx[n] = bf16( xh[n]*dis[n]^2 + sum_{s in in(n)} xh[s]*dis[s]*dis[n] )
// one wave per node, 16-deep pipelined gather; all table reads bf16
__global__ __launch_bounds__(256) void gather_kernel(const unsigned short* __restrict__ xh,
                                                     const int* __restrict__ rowptr,
                                                     const int* __restrict__ rowlen,
                                                     const int* __restrict__ csrc,
                                                     const float* __restrict__ dis,
                                                     unsigned short* __restrict__ aggx) {
    int wid = (blockIdx.x * 256 + threadIdx.x) >> 6;
    int lane = threadIdx.x & 63;
    if (wid >= N_NODES) return;
    int start = rowptr[wid];
    int len = rowlen[wid];
    float dd = dis[wid];
    float self = bf2f(xh[(size_t)wid * 64 + lane]);
    float acc = self * dd * dd;
    for (int j0 = 0; j0 < len; j0 += 64) {
        int cnt = min(64, len - j0);
        int sv = 0;
        float wv = 0.f;
        if (lane < cnt) {
            sv = csrc[start + j0 + lane];
            wv = dis[sv] * dd;
        }
        int iters = (cnt + 15) & ~15;
        for (int k = 0; k < iters; k += 16) {
            int s[16]; float w[16], v[16];
#pragma unroll
            for (int u = 0; u < 16; ++u) {
                s[u] = __shfl(sv, k + u);
                w[u] = __shfl(wv, k + u);
            }
#pragma unroll
            for (int u = 0; u < 16; ++u)
                v[u] = bf2f(xh[(size_t)s[u] * 64 + lane]);
#pragma unroll
            for (int u = 0; u < 16; ++u) acc = fmaf(v[u], w[u], acc);
        }
    }
    aggx[(size_t)wid * 64 + lane] = f2bf(acc);
}

// partial second moments, atomically accumulated into M[64][64] and CS[64] (bf16 input)
__global__ __launch_bounds__(256) void moment_kernel(const unsigned short* __restrict__ aggx,
                                                     float* __restrict__ M,
                                                     float* __restrict__ CS) {
    __shared__ float rows[8 * 64];
    int c = blockIdx.x, tid = threadIdx.x;
    int r0 = c * CHUNK_ROWS;
    int r1 = min(r0 + CHUNK_ROWS, N_NODES);
    int i0 = (tid >> 6) * 16;
    int j = tid & 63;
    float acc[16] = {};
    float cs = 0.f;
    for (int it = 0; it < (CHUNK_ROWS + 7) / 8; ++it) {
        int sid = tid * 2;
        int grow = r0 + it * 8 + (sid >> 6);
        float2 v = {0.f, 0.f};
        if (grow < r1) {
            ushort2 h = *(const ushort2*)(aggx + (size_t)(r0 + it * 8) * 64 + sid);
            v.x = bf2f(h.x); v.y = bf2f(h.y);
        }
        __syncthreads();
        *(float2*)(rows + sid) = v;
        __syncthreads();
#pragma unroll
        for (int rr = 0; rr < 8; ++rr) {
            float bj = rows[rr * 64 + j];
            float4 a0 = *(const float4*)(rows + rr * 64 + i0);
            float4 a1 = *(const float4*)(rows + rr * 64 + i0 + 4);
            float4 a2 = *(const float4*)(rows + rr * 64 + i0 + 8);
            float4 a3 = *(const float4*)(rows + rr * 64 + i0 + 12);
            acc[0]  += a0.x * bj; acc[1]  += a0.y * bj; acc[2]  += a0.z * bj; acc[3]  += a0.w * bj;
            acc[4]  += a1.x * bj; acc[5]  += a1.y * bj; acc[6]  += a1.z * bj; acc[7]  += a1.w * bj;
            acc[8]  += a2.x * bj; acc[9]  += a2.y * bj; acc[10] += a2.z * bj; acc[11] += a2.w * bj;
            acc[12] += a3.x * bj; acc[13] += a3.y * bj; acc[14] += a3.z * bj; acc[15] += a3.w * bj;
        }
        if (tid < 64) {
#pragma unroll
            for (int rr = 0; rr < 8; ++rr) cs += rows[rr * 64 + tid];
        }
    }
#pragma unroll
    for (int m = 0; m < 16; ++m)
        unsafeAtomicAdd(&M[(i0 + m) * 64 + j], acc[m]);
    if (tid < 64) unsafeAtomicAdd(&CS[tid], cs);
}

// folded BN1 scale/shift: one block per output column j, 64 threads, no per-thread arrays
// var_j = (w_j^T M w_j)/N - my_j^2 ; my_j = (CS . w_j)/N   (b_gcn cancels)
__global__ __launch_bounds__(64) void fold_kernel(const float* __restrict__ M,
                                                  const float* __restrict__ CS,
                                                  const float* __restrict__ W,
                                                  const float* __restrict__ g1,
                                                  const float* __restrict__ be1,
                                                  float* __restrict__ scale1,
                                                  float* __restrict__ shiftp) {
    __shared__ float wcol[64];
    int j = blockIdx.x;
    int lane = threadIdx.x;
    wcol[lane] = W[lane * 128 + j];
    __syncthreads();
    float wl = wcol[lane];
    float t = 0.f;
    const float* Mrow = M + lane * 64;
#pragma unroll 16
    for (int k = 0; k < 64; ++k) t += Mrow[k] * wcol[k];
    float part = t * wl;
    float csp = CS[lane] * wl;
#pragma unroll
    for (int off = 32; off; off >>= 1) {
        part += __shfl_xor(part, off);
        csp  += __shfl_xor(csp, off);
    }
    if (lane == 0) {
        float Ey2 = part * (1.0f / N_NODES);
        float my = csp * (1.0f / N_NODES);
        float var = Ey2 - my * my;
        float sc = g1[j] * rsqrtf(var + EPS);
        scale1[j] = sc;
        shiftp[j] = be1[j] - my * sc;
    }
}

// fused: y = aggx_tile @ W, z = relu(y*sc+sh), segment-run atomicAdd into psum[g][c]
// (gnn_batch sorted -> a 16-row tile spans 1-3 graphs); bf16 aggx input
__global__ __launch_bounds__(256) void gemm_pool_kernel(const unsigned short* __restrict__ aggx,
                                                        const int* __restrict__ gbatch,
                                                        const float* __restrict__ W,
                                                        const float* __restrict__ scale1,
                                                        const float* __restrict__ shiftp,
                                                        float* __restrict__ psum) {
    __shared__ float Ws[64 * 128];   // 32KB
    __shared__ float As[16 * 64];    // 4KB
    __shared__ float Zs[16 * 128];   // 8KB
    __shared__ int gid[16];
    int tid = threadIdx.x;
    const float4* W4 = (const float4*)W;
    float4* Ws4 = (float4*)Ws;
#pragma unroll
    for (int i = 0; i < 8; ++i) Ws4[tid + i * 256] = W4[tid + i * 256];
    int row0 = blockIdx.x * 16;
    {
        ushort4 h = ((const ushort4*)(aggx + (size_t)row0 * 64))[tid];
        float4 f; f.x = bf2f(h.x); f.y = bf2f(h.y); f.z = bf2f(h.z); f.w = bf2f(h.w);
        ((float4*)As)[tid] = f;
    }
    if (tid < 16) gid[tid] = gbatch[row0 + tid];
    __syncthreads();
    int tx = tid & 31;
    int ty = tid >> 5;
    int r0 = ty * 2;
    float4 sc4 = ((const float4*)scale1)[tx];
    float4 sh4 = ((const float4*)shiftp)[tx];
    float acc[2][4] = {};
#pragma unroll
    for (int k = 0; k < 64; ++k) {
        float a0 = As[r0 * 64 + k];
        float a1 = As[(r0 + 1) * 64 + k];
        float4 w = Ws4[k * 32 + tx];
        acc[0][0] += a0 * w.x; acc[0][1] += a0 * w.y; acc[0][2] += a0 * w.z; acc[0][3] += a0 * w.w;
        acc[1][0] += a1 * w.x; acc[1][1] += a1 * w.y; acc[1][2] += a1 * w.z; acc[1][3] += a1 * w.w;
    }
#pragma unroll
    for (int rr = 0; rr < 2; ++rr) {
        float4 z;
        z.x = fmaxf(acc[rr][0] * sc4.x + sh4.x, 0.f);
        z.y = fmaxf(acc[rr][1] * sc4.y + sh4.y, 0.f);
        z.z = fmaxf(acc[rr][2] * sc4.z + sh4.z, 0.f);
        z.w = fmaxf(acc[rr][3] * sc4.w + sh4.w, 0.f);
        ((float4*)(Zs + (r0 + rr) * 128))[tx] = z;
    }
    __syncthreads();
    if (tid < 128) {
        int c = tid;
        float a = 0.f;
        int g = gid[0];
#pragma unroll
        for (int i = 0; i < 16; ++i) {
            int gi = gid[i];
            if (gi != g) {
                unsafeAtomicAdd(&psum[(size_t)g * 128 + c], a);
                a = 0.f;
                g = gi;
            }
            a += Zs[i * 128 + c];
        }
        unsafeAtomicAdd(&psum[(size_t)g * 128 + c], a);
    }
}

// t1 = (psum/cnt) @ W_lin1 + b ; stats1 += (sum, sumsq)
__global__ __launch_bounds__(256) void lin1_kernel(const float* __restrict__ psum,
                                                   const int* __restrict__ gstart,
                                                   const float* __restrict__ W,
                                                   const float* __restrict__ bias,
                                                   float* __restrict__ t1,
                                                   float* __restrict__ stats1) {
    __shared__ float ls[256], ls2[256];
    int tid = threadIdx.x;
    int r = blockIdx.x * 4 + (tid >> 6);
    int c = tid & 63;
    float invc = 1.0f / fmaxf((float)(gstart[r + 1] - gstart[r]), 1.0f);
    float acc = 0.f;
    const float* srow = psum + (size_t)r * 128;
#pragma unroll 8
    for (int k = 0; k < 128; ++k)
        acc += srow[k] * W[k * 64 + c];
    acc = bias[c] + acc * invc;
    t1[r * 64 + c] = acc;
    ls[tid] = acc; ls2[tid] = acc * acc;
    __syncthreads();
    if (tid < 64) {
        float s = ls[tid] + ls[tid + 64] + ls[tid + 128] + ls[tid + 192];
        float q = ls2[tid] + ls2[tid + 64] + ls2[tid + 128] + ls2[tid + 192];
        unsafeAtomicAdd(&stats1[c], s);
        unsafeAtomicAdd(&stats1[64 + c], q);
    }
}

// t2 = relu(bn(t1; g2,be2)) @ W_lin2 + b ; stats2
__global__ __launch_bounds__(256) void lin2_kernel(const float* __restrict__ t1,
                                                   const float* __restrict__ stats1,
                                                   const float* __restrict__ g,
                                                   const float* __restrict__ be,
                                                   const float* __restrict__ W,
                                                   const float* __restrict__ bias,
                                                   float* __restrict__ t2,
                                                   float* __restrict__ stats2) {
    __shared__ float sc[64], sh[64];
    __shared__ float ls[256], ls2[256];
    int tid = threadIdx.x;
    if (tid < 64) {
        float m = stats1[tid] * (1.0f / BSZ);
        float var = stats1[64 + tid] * (1.0f / BSZ) - m * m;
        float s = g[tid] * rsqrtf(var + EPS);
        sc[tid] = s; sh[tid] = be[tid] - m * s;
    }
    __syncthreads();
    int r = blockIdx.x * 4 + (tid >> 6);
    int c = tid & 63;
    float acc = bias[c];
    const float* row = t1 + (size_t)r * 64;
#pragma unroll 8
    for (int k = 0; k < 64; ++k) {
        float z = fmaxf(row[k] * sc[k] + sh[k], 0.f);
        acc += z * W[k * 64 + c];
    }
    t2[r * 64 + c] = acc;
    ls[tid] = acc; ls2[tid] = acc * acc;
    __syncthreads();
    if (tid < 64) {
        float s = ls[tid] + ls[tid + 64] + ls[tid + 128] + ls[tid + 192];
        float q = ls2[tid] + ls2[tid + 64] + ls2[tid + 128] + ls2[tid + 192];
        unsafeAtomicAdd(&stats2[c], s);
        unsafeAtomicAdd(&stats2[64 + c], q);
    }
}

// t4 = concat(x, bn(t2;g3,be3)[masks]) @ W_fc1 + b ; stats4
__global__ __launch_bounds__(1024) void fc1_kernel(const float* __restrict__ x,
                                                   const int* __restrict__ masks,
                                                   const float* __restrict__ t2,
                                                   const float* __restrict__ stats2,
                                                   const float* __restrict__ g3,
                                                   const float* __restrict__ be3,
                                                   const float* __restrict__ W,
                                                   const float* __restrict__ bias,
                                                   float* __restrict__ t4,
                                                   float* __restrict__ stats4) {
    __shared__ float sc[64], sh[64];
    __shared__ float cat[4][128];
    __shared__ float ls[1024], ls2[1024];
    int tid = threadIdx.x;
    if (tid < 64) {
        float m = stats2[tid] * (1.0f / BSZ);
        float var = stats2[64 + tid] * (1.0f / BSZ) - m * m;
        float s = g3[tid] * rsqrtf(var + EPS);
        sc[tid] = s; sh[tid] = be3[tid] - m * s;
    }
    __syncthreads();
    int r0 = blockIdx.x * 4;
    if (tid < 512) {
        int i = tid >> 7;
        int k = tid & 127;
        int r = r0 + i;
        float v;
        if (k < 64) {
            v = x[r * 64 + k];
        } else {
            int mrow = masks[r];
            int kk = k - 64;
            v = t2[mrow * 64 + kk] * sc[kk] + sh[kk];
        }
        cat[i][k] = v;
    }
    __syncthreads();
    int i = tid >> 8;
    int c = tid & 255;
    float acc = bias[c];
#pragma unroll 8
    for (int k = 0; k < 128; ++k)
        acc += cat[i][k] * W[k * 256 + c];
    t4[(size_t)(r0 + i) * 256 + c] = acc;
    ls[tid] = acc; ls2[tid] = acc * acc;
    __syncthreads();
    if (tid < 256) {
        float s = ls[tid] + ls[tid + 256] + ls[tid + 512] + ls[tid + 768];
        float q = ls2[tid] + ls2[tid + 256] + ls2[tid + 512] + ls2[tid + 768];
        unsafeAtomicAdd(&stats4[c], s);
        unsafeAtomicAdd(&stats4[256 + c], q);
    }
}

// t5 = (relu(bn(t4;g4,be4))^2) @ W_fc2 + b ; stats5
__global__ __launch_bounds__(256) void fc2_kernel(const float* __restrict__ t4,
                                                  const float* __restrict__ stats4,
                                                  const float* __restrict__ g4,
                                                  const float* __restrict__ be4,
                                                  const float* __restrict__ W,
                                                  const float* __restrict__ bias,
                                                  float* __restrict__ t5,
                                                  float* __restrict__ stats5) {
    __shared__ float sc[256], sh[256];
    __shared__ float ls[256], ls2[256];
    int tid = threadIdx.x;
    {
        float m = stats4[tid] * (1.0f / BSZ);
        float var = stats4[256 + tid] * (1.0f / BSZ) - m * m;
        float s = g4[tid] * rsqrtf(var + EPS);
        sc[tid] = s; sh[tid] = be4[tid] - m * s;
    }
    __syncthreads();
    int r = blockIdx.x * 4 + (tid >> 6);
    int c = tid & 63;
    float acc = bias[c];
    const float* row = t4 + (size_t)r * 256;
#pragma unroll 8
    for (int k = 0; k < 256; ++k) {
        float z = fmaxf(row[k] * sc[k] + sh[k], 0.f);
        z *= z;
        acc += z * W[k * 64 + c];
    }
    t5[r * 64 + c] = acc;
    ls[tid] = acc; ls2[tid] = acc * acc;
    __syncthreads();
    if (tid < 64) {
        float s = ls[tid] + ls[tid + 64] + ls[tid + 128] + ls[tid + 192];
        float q = ls2[tid] + ls2[tid + 64] + ls2[tid + 128] + ls2[tid + 192];
        unsafeAtomicAdd(&stats5[c], s);
        unsafeAtomicAdd(&stats5[64 + c], q);
    }
}

// out = ((relu(bn(t5;g5,be5)))^4) @ W_fc3 + b
__global__ __launch_bounds__(256) void fc3_kernel(const float* __restrict__ t5,
                                                  const float* __restrict__ stats5,
                                                  const float* __restrict__ g5,
                                                  const float* __restrict__ be5,
                                                  const float* __restrict__ W,
                                                  const float* __restrict__ bias,
                                                  float* __restrict__ out) {
    __shared__ float sc[64], sh[64];
    int tid = threadIdx.x;
    if (tid < 64) {
        float m = stats5[tid] * (1.0f / BSZ);
        float var = stats5[64 + tid] * (1.0f / BSZ) - m * m;
        float s = g5[tid] * rsqrtf(var + EPS);
        sc[tid] = s; sh[tid] = be5[tid] - m * s;
    }
    __syncthreads();
    int r = blockIdx.x * 256 + tid;
    float acc = bias[0];
    const float* row = t5 + (size_t)r * 64;
#pragma unroll
    for (int k = 0; k < 64; ++k) {
        float z = fmaxf(row[k] * sc[k] + sh[k], 0.f);
        z = z * z;
        z = z * z;
        acc += z * W[k];
    }
    out[r] = acc;
}

extern "C" void kernel_launch(void* const* d_in, const int* in_sizes, int n_in,
                              void* d_out, int out_size, void* d_ws, size_t ws_size,
                              hipStream_t stream) {
    const float* x      = (const float*)d_in[0];
    const int*   masks  = (const int*)d_in[1];
    const float* gnn_x  = (const float*)d_in[2];
    const int*   ei     = (const int*)d_in[3];
    const int*   gbatch = (const int*)d_in[4];
    const float* W_gcn  = (const float*)d_in[5];
    const float* b_gcn  = (const float*)d_in[6];   // cancels in folded BN1
    const float* g1     = (const float*)d_in[7];
    const float* be1    = (const float*)d_in[8];
    const float* W_lin1 = (const float*)d_in[9];
    const float* b_lin1 = (const float*)d_in[10];
    const float* g2     = (const float*)d_in[11];
    const float* be2    = (const float*)d_in[12];
    const float* W_lin2 = (const float*)d_in[13];
    const float* b_lin2 = (const float*)d_in[14];
    const float* g3     = (const float*)d_in[15];
    const float* be3    = (const float*)d_in[16];
    const float* W_fc1  = (const float*)d_in[17];
    const float* b_fc1  = (const float*)d_in[18];
    const float* g4     = (const float*)d_in[19];
    const float* be4    = (const float*)d_in[20];
    const float* W_fc2  = (const float*)d_in[21];
    const float* b_fc2  = (const float*)d_in[22];
    const float* g5     = (const float*)d_in[23];
    const float* be5    = (const float*)d_in[24];
    const float* W_fc3  = (const float*)d_in[25];
    const float* b_fc3  = (const float*)d_in[26];
    (void)b_gcn;

    float* ws = (float*)d_ws;
    float* psum   = ws + WS_PSUM;
    float* stats1 = ws + WS_STATS1;
    float* stats2 = ws + WS_STATS2;
    float* stats4 = ws + WS_STATS4;
    float* stats5 = ws + WS_STATS5;
    float* Mbuf   = ws + WS_M;
    float* CSbuf  = ws + WS_CS;
    int*   gcur   = (int*)(ws + WS_GCUR);
    float* scale1 = ws + WS_SCALE1;
    float* shiftp = ws + WS_SHIFTP;
    int*   gstart = (int*)(ws + WS_GSTART);
    float* dis    = ws + WS_DIS;
    int*   rowptr = (int*)(ws + WS_ROWPTR);
    int*   rowlen = (int*)(ws + WS_ROWLEN);
    unsigned int* packed = (unsigned int*)(ws + WS_PACKED);
    int*   csrc   = (int*)(ws + WS_CSRC);
    unsigned short* xh   = (unsigned short*)(ws + WS_XH);
    unsigned short* aggx = (unsigned short*)(ws + WS_AGGX);
    float* t1     = ws + WS_T1;
    float* t2     = ws + WS_T2;
    float* t4     = ws + WS_T4;
    float* t5     = ws + WS_T5;
    float* out    = (float*)d_out;

    prep_cvt_kernel<<<CVT_BLOCKS + 21, 256, 0, stream>>>(ws, gbatch, gnn_x, xh);
    bin_kernel<<<BIN_BLOCKS, 512, 0, stream>>>(ei, gcur, packed);
    csr_build_kernel<<<NBUCK, 512, 0, stream>>>(packed, gcur, rowptr, rowlen, csrc, dis);
    gather_kernel<<<(N_NODES * 64 + 255) / 256, 256, 0, stream>>>(xh, rowptr, rowlen, csrc, dis, aggx);
    moment_kernel<<<NCHUNK, 256, 0, stream>>>(aggx, Mbuf, CSbuf);
    fold_kernel<<<128, 64, 0, stream>>>(Mbuf, CSbuf, W_gcn, g1, be1, scale1, shiftp);
    gemm_pool_kernel<<<N_NODES / 16, 256, 0, stream>>>(aggx, gbatch, W_gcn, scale1, shiftp, psum);
    lin1_kernel<<<256, 256, 0, stream>>>(psum, gstart, W_lin1, b_lin1, t1, stats1);
    lin2_kernel<<<256, 256, 0, stream>>>(t1, stats1, g2, be2, W_lin2, b_lin2, t2, stats2);
    fc1_kernel<<<256, 1024, 0, stream>>>(x, masks, t2, stats2, g3, be3, W_fc1, b_fc1, t4, stats4);
    fc2_kernel<<<256, 256, 0, stream>>>(t4, stats4, g4, be4, W_fc2, b_fc2, t5, stats5);
    fc3_kernel<<<4, 256, 0, stream>>>(t5, stats5, g5, be5, W_fc3, b_fc3, out);
}

// Round 12
// 236.976 us; speedup vs baseline: 3.2077x; 1.0008x over previous
//
#include <hip/hip_runtime.h>
#include <hip/hip_bf16.h>

#define N_NODES 100000
#define N_EDGES 1600000
#define N_GRAPHS 1024
#define BSZ 1024
#define EPS 1e-5f

#define NBUCK 256
#define BUCKW 391          // ceil(100000/256)
#define BCAP  8192         // static per-bucket edge capacity (mean 6250, sd 79)
#define SRC_MASK 0x1FFFF   // 17 bits for src (<131072)
#define BIN_CHUNK 4096
#define BIN_BLOCKS 391     // ceil(1600000/4096)
#define NCHUNK 512         // moment row-chunks
#define CHUNK_ROWS 196     // 512*196 = 100352 >= 100000
#define CVT_BLOCKS 6250    // 100000*64/4/256

// ---------------- workspace layout (4-byte units) ----------------
// zeroed-every-call region:
#define WS_PSUM    0          // 1024*128 pooled sums
#define WS_STATS1  131072     // 128
#define WS_STATS2  131200     // 128
#define WS_STATS4  131328     // 512
#define WS_STATS5  131840     // 128
#define WS_M       131968     // 4096 (aggx^T aggx)
#define WS_CS      136064     // 64 (aggx column sums)
#define WS_ZTOTAL  136128
// written-before-read region:
#define WS_GCUR    136128     // 256 int (init to b*BCAP by prep)
#define WS_SCALE1  136384     // 128
#define WS_SHIFTP  136512     // 128
#define WS_GSTART  136640     // 1025 int (pad to 137668)
#define WS_DIS     137668     // 100000 float -> 237668
#define WS_ROWPTR  237668     // 100000 int -> 337668
#define WS_ROWLEN  337668     // 100000 int -> 437668
#define WS_PACKED  437668     // 256*8192 u32 -> 2534820
#define WS_CSRC    2534820    // 256*8192 int -> 4631972
#define WS_XH      4631972    // 100000*64 ushort = 3200000 words -> 7831972
#define WS_AGGX    7831972    // 100000*64 ushort = 3200000 words -> 11031972
#define WS_T1      11031972   // 1024*64 -> 11097508
#define WS_T2      11097508   // 1024*64 -> 11163044
#define WS_T4      11163044   // 1024*256 -> 11425188
#define WS_T5      11425188   // 1024*64 -> 11490724
// total = 11490724 words = ~46 MB

__device__ inline unsigned short f2bf(float f) {
    unsigned int u = __float_as_uint(f);
    return (unsigned short)((u + 0x7FFFu + ((u >> 16) & 1u)) >> 16);
}
__device__ inline float bf2f(unsigned short h) {
    return __uint_as_float((unsigned int)h << 16);
}

// blocks 0..6249: fp32->bf16 convert; 6250..6265: zero; 6266: gcur; 6267..6270: graph bounds
__global__ __launch_bounds__(256) void prep_cvt_kernel(float* __restrict__ ws,
                                                       const int* __restrict__ gbatch,
                                                       const float* __restrict__ x,
                                                       unsigned short* __restrict__ xh) {
    int b = blockIdx.x, tid = threadIdx.x;
    if (b < CVT_BLOCKS) {
        int i = b * 256 + tid;
        float4 f = ((const float4*)x)[i];
        ushort4 h;
        h.x = f2bf(f.x); h.y = f2bf(f.y); h.z = f2bf(f.z); h.w = f2bf(f.w);
        ((ushort4*)xh)[i] = h;
    } else if (b < CVT_BLOCKS + 16) {
        for (int i = (b - CVT_BLOCKS) * 256 + tid; i < WS_ZTOTAL; i += 16 * 256) ws[i] = 0.0f;
    } else if (b == CVT_BLOCKS + 16) {
        ((int*)(ws + WS_GCUR))[tid] = tid * BCAP;
    } else {
        int g = (b - (CVT_BLOCKS + 17)) * 256 + tid;
        int lo = 0, hi = N_NODES;
        while (lo < hi) {
            int mid = (lo + hi) >> 1;
            if (gbatch[mid] < g) lo = mid + 1; else hi = mid;
        }
        int* gstart = (int*)(ws + WS_GSTART);
        gstart[g] = lo;
        if (g == 0) gstart[N_GRAPHS] = N_NODES;
    }
}

// bin edges into 256 coarse dst-buckets (static BCAP stride) with LDS staging
__global__ __launch_bounds__(512) void bin_kernel(const int* __restrict__ ei,
                                                  int* __restrict__ gcursor,
                                                  unsigned int* __restrict__ packed) {
    __shared__ unsigned int stage[BIN_CHUNK];   // 16KB
    __shared__ int lh[NBUCK], lbase[NBUCK], lcur[NBUCK], gb[NBUCK];
    const int* src = ei;
    const int* dst = ei + N_EDGES;
    int tid = threadIdx.x;
    int base = blockIdx.x * BIN_CHUNK;
    int n = min(BIN_CHUNK, N_EDGES - base);
    if (tid < NBUCK) lh[tid] = 0;
    __syncthreads();
    for (int i = tid; i < n; i += 512)
        atomicAdd(&lh[dst[base + i] / BUCKW], 1);
    __syncthreads();
    if (tid < NBUCK) lbase[tid] = lh[tid];
    __syncthreads();
    for (int off = 1; off < NBUCK; off <<= 1) {
        int t = (tid < NBUCK && tid >= off) ? lbase[tid - off] : 0;
        __syncthreads();
        if (tid < NBUCK) lbase[tid] += t;
        __syncthreads();
    }
    if (tid < NBUCK) {
        int excl = lbase[tid] - lh[tid];
        lbase[tid] = excl;
        lcur[tid] = excl;
        gb[tid] = atomicAdd(&gcursor[tid], lh[tid]);
    }
    __syncthreads();
    for (int i = tid; i < n; i += 512) {
        int d = dst[base + i];
        int s = src[base + i];
        int bk = d / BUCKW;
        int dl = d - bk * BUCKW;
        int slot = atomicAdd(&lcur[bk], 1);
        stage[slot] = ((unsigned int)dl << 17) | (unsigned int)s;
    }
    __syncthreads();
    int wid = tid >> 6, lane = tid & 63;
    for (int bk = wid; bk < NBUCK; bk += 8) {
        int lo = lbase[bk], go = gb[bk];
        int len = min(lh[bk], (bk + 1) * BCAP - go);  // overflow clamp (never expected)
        for (int j = lane; j < len; j += 64)
            packed[go + j] = stage[lo + j];
    }
}

// per-bucket: exact CSR via single global read (pk staged in LDS) + rowptr/rowlen + dis
__global__ __launch_bounds__(512) void csr_build_kernel(const unsigned int* __restrict__ packed,
                                                        const int* __restrict__ gcur,
                                                        int* __restrict__ rowptr,
                                                        int* __restrict__ rowlen,
                                                        int* __restrict__ csrc,
                                                        float* __restrict__ dis) {
    __shared__ unsigned int pk[BCAP]; // 32KB  (single global read of packed)
    __shared__ int dcnt[BUCKW];
    __shared__ int lcur[BUCKW];
    __shared__ int stage[BCAP];       // 32KB
    int b = blockIdx.x, tid = threadIdx.x;
    int e0 = b * BCAP;
    int ecnt = min(gcur[b] - e0, BCAP);
    int nbase = b * BUCKW;
    int nmax = min(BUCKW, N_NODES - nbase);
    for (int i = tid; i < BUCKW; i += 512) dcnt[i] = 0;
    __syncthreads();
    for (int i = tid; i < ecnt; i += 512) {
        unsigned int r = packed[e0 + i];
        pk[i] = r;
        atomicAdd(&dcnt[r >> 17], 1);
    }
    __syncthreads();
    for (int i = tid; i < nmax; i += 512) {
        dis[nbase + i] = rsqrtf((float)dcnt[i] + 1.0f);
        rowlen[nbase + i] = dcnt[i];
    }
    __syncthreads();
    if (tid < 64) {
        int lane = tid;
        int run = 0;
        for (int c = 0; c < BUCKW; c += 64) {
            int idx = c + lane;
            int v = (idx < BUCKW) ? dcnt[idx] : 0;
            int inc = v;
#pragma unroll
            for (int off = 1; off < 64; off <<= 1) {
                int t = __shfl_up(inc, off);
                if (lane >= off) inc += t;
            }
            if (idx < BUCKW) {
                int excl = run + inc - v;
                dcnt[idx] = excl;
                lcur[idx] = excl;
            }
            run += __shfl(inc, 63);
        }
    }
    __syncthreads();
    for (int i = tid; i < nmax; i += 512)
        rowptr[nbase + i] = e0 + dcnt[i];
    for (int i = tid; i < ecnt; i += 512) {
        unsigned int r = pk[i];
        int slot = atomicAdd(&lcur[r >> 17], 1);
        stage[slot] = (int)(r & SRC_MASK);
    }
    __syncthreads();
    for (int i = tid; i < ecnt; i += 512) csrc[e0 + i] = stage[i];
}

// aggx[n] = bf16( xh[n]*dis[n]^2 + sum_{s in in(n)} xh[s]*dis[s]*dis[n] )
// one wave per node, 8-deep pipelined gather; all table reads bf16
__global__ __launch_bounds__(256) void gather_kernel(const unsigned short* __restrict__ xh,
                                                     const int* __restrict__ rowptr,
                                                     const int* __restrict__ rowlen,
                                                     const int* __restrict__ csrc,
                                                     const float* __restrict__ dis,
                                                     unsigned short* __restrict__ aggx) {
    int wid = (blockIdx.x * 256 + threadIdx.x) >> 6;
    int lane = threadIdx.x & 63;
    if (wid >= N_NODES) return;
    int start = rowptr[wid];
    int len = rowlen[wid];
    float dd = dis[wid];
    float self = bf2f(xh[(size_t)wid * 64 + lane]);
    float acc = self * dd * dd;
    for (int j0 = 0; j0 < len; j0 += 64) {
        int cnt = min(64, len - j0);
        int sv = 0;
        float wv = 0.f;
        if (lane < cnt) {
            sv = csrc[start + j0 + lane];
            wv = dis[sv] * dd;
        }
        int iters = (cnt + 7) & ~7;
        for (int k = 0; k < iters; k += 8) {
            int s[8]; float w[8], v[8];
#pragma unroll
            for (int u = 0; u < 8; ++u) {
                s[u] = __shfl(sv, k + u);
                w[u] = __shfl(wv, k + u);
            }
#pragma unroll
            for (int u = 0; u < 8; ++u)
                v[u] = bf2f(xh[(size_t)s[u] * 64 + lane]);
#pragma unroll
            for (int u = 0; u < 8; ++u) acc = fmaf(v[u], w[u], acc);
        }
    }
    aggx[(size_t)wid * 64 + lane] = f2bf(acc);
}

// partial second moments, atomically accumulated into M[64][64] and CS[64] (bf16 input)
__global__ __launch_bounds__(256) void moment_kernel(const unsigned short* __restrict__ aggx,
                                                     float* __restrict__ M,
                                                     float* __restrict__ CS) {
    __shared__ float rows[8 * 64];
    int c = blockIdx.x, tid = threadIdx.x;
    int r0 = c * CHUNK_ROWS;
    int r1 = min(r0 + CHUNK_ROWS, N_NODES);
    int i0 = (tid >> 6) * 16;
    int j = tid & 63;
    float acc[16] = {};
    float cs = 0.f;
    for (int it = 0; it < (CHUNK_ROWS + 7) / 8; ++it) {
        int sid = tid * 2;
        int grow = r0 + it * 8 + (sid >> 6);
        float2 v = {0.f, 0.f};
        if (grow < r1) {
            ushort2 h = *(const ushort2*)(aggx + (size_t)(r0 + it * 8) * 64 + sid);
            v.x = bf2f(h.x); v.y = bf2f(h.y);
        }
        __syncthreads();
        *(float2*)(rows + sid) = v;
        __syncthreads();
#pragma unroll
        for (int rr = 0; rr < 8; ++rr) {
            float bj = rows[rr * 64 + j];
            float4 a0 = *(const float4*)(rows + rr * 64 + i0);
            float4 a1 = *(const float4*)(rows + rr * 64 + i0 + 4);
            float4 a2 = *(const float4*)(rows + rr * 64 + i0 + 8);
            float4 a3 = *(const float4*)(rows + rr * 64 + i0 + 12);
            acc[0]  += a0.x * bj; acc[1]  += a0.y * bj; acc[2]  += a0.z * bj; acc[3]  += a0.w * bj;
            acc[4]  += a1.x * bj; acc[5]  += a1.y * bj; acc[6]  += a1.z * bj; acc[7]  += a1.w * bj;
            acc[8]  += a2.x * bj; acc[9]  += a2.y * bj; acc[10] += a2.z * bj; acc[11] += a2.w * bj;
            acc[12] += a3.x * bj; acc[13] += a3.y * bj; acc[14] += a3.z * bj; acc[15] += a3.w * bj;
        }
        if (tid < 64) {
#pragma unroll
            for (int rr = 0; rr < 8; ++rr) cs += rows[rr * 64 + tid];
        }
    }
#pragma unroll
    for (int m = 0; m < 16; ++m)
        unsafeAtomicAdd(&M[(i0 + m) * 64 + j], acc[m]);
    if (tid < 64) unsafeAtomicAdd(&CS[tid], cs);
}

// folded BN1 scale/shift: one block per output column j, 64 threads, no per-thread arrays
// var_j = (w_j^T M w_j)/N - my_j^2 ; my_j = (CS . w_j)/N   (b_gcn cancels)
__global__ __launch_bounds__(64) void fold_kernel(const float* __restrict__ M,
                                                  const float* __restrict__ CS,
                                                  const float* __restrict__ W,
                                                  const float* __restrict__ g1,
                                                  const float* __restrict__ be1,
                                                  float* __restrict__ scale1,
                                                  float* __restrict__ shiftp) {
    __shared__ float wcol[64];
    int j = blockIdx.x;
    int lane = threadIdx.x;
    wcol[lane] = W[lane * 128 + j];
    __syncthreads();
    float wl = wcol[lane];
    float t = 0.f;
    const float* Mrow = M + lane * 64;
#pragma unroll 16
    for (int k = 0; k < 64; ++k) t += Mrow[k] * wcol[k];
    float part = t * wl;
    float csp = CS[lane] * wl;
#pragma unroll
    for (int off = 32; off; off >>= 1) {
        part += __shfl_xor(part, off);
        csp  += __shfl_xor(csp, off);
    }
    if (lane == 0) {
        float Ey2 = part * (1.0f / N_NODES);
        float my = csp * (1.0f / N_NODES);
        float var = Ey2 - my * my;
        float sc = g1[j] * rsqrtf(var + EPS);
        scale1[j] = sc;
        shiftp[j] = be1[j] - my * sc;
    }
}

// fused: y = aggx_tile @ W, z = relu(y*sc+sh), segment-run atomicAdd into psum[g][c]
// (gnn_batch sorted -> a 16-row tile spans 1-3 graphs); bf16 aggx input
__global__ __launch_bounds__(256) void gemm_pool_kernel(const unsigned short* __restrict__ aggx,
                                                        const int* __restrict__ gbatch,
                                                        const float* __restrict__ W,
                                                        const float* __restrict__ scale1,
                                                        const float* __restrict__ shiftp,
                                                        float* __restrict__ psum) {
    __shared__ float Ws[64 * 128];   // 32KB
    __shared__ float As[16 * 64];    // 4KB
    __shared__ float Zs[16 * 128];   // 8KB
    __shared__ int gid[16];
    int tid = threadIdx.x;
    const float4* W4 = (const float4*)W;
    float4* Ws4 = (float4*)Ws;
#pragma unroll
    for (int i = 0; i < 8; ++i) Ws4[tid + i * 256] = W4[tid + i * 256];
    int row0 = blockIdx.x * 16;
    {
        ushort4 h = ((const ushort4*)(aggx + (size_t)row0 * 64))[tid];
        float4 f; f.x = bf2f(h.x); f.y = bf2f(h.y); f.z = bf2f(h.z); f.w = bf2f(h.w);
        ((float4*)As)[tid] = f;
    }
    if (tid < 16) gid[tid] = gbatch[row0 + tid];
    __syncthreads();
    int tx = tid & 31;
    int ty = tid >> 5;
    int r0 = ty * 2;
    float4 sc4 = ((const float4*)scale1)[tx];
    float4 sh4 = ((const float4*)shiftp)[tx];
    float acc[2][4] = {};
#pragma unroll
    for (int k = 0; k < 64; ++k) {
        float a0 = As[r0 * 64 + k];
        float a1 = As[(r0 + 1) * 64 + k];
        float4 w = Ws4[k * 32 + tx];
        acc[0][0] += a0 * w.x; acc[0][1] += a0 * w.y; acc[0][2] += a0 * w.z; acc[0][3] += a0 * w.w;
        acc[1][0] += a1 * w.x; acc[1][1] += a1 * w.y; acc[1][2] += a1 * w.z; acc[1][3] += a1 * w.w;
    }
#pragma unroll
    for (int rr = 0; rr < 2; ++rr) {
        float4 z;
        z.x = fmaxf(acc[rr][0] * sc4.x + sh4.x, 0.f);
        z.y = fmaxf(acc[rr][1] * sc4.y + sh4.y, 0.f);
        z.z = fmaxf(acc[rr][2] * sc4.z + sh4.z, 0.f);
        z.w = fmaxf(acc[rr][3] * sc4.w + sh4.w, 0.f);
        ((float4*)(Zs + (r0 + rr) * 128))[tx] = z;
    }
    __syncthreads();
    if (tid < 128) {
        int c = tid;
        float a = 0.f;
        int g = gid[0];
#pragma unroll
        for (int i = 0; i < 16; ++i) {
            int gi = gid[i];
            if (gi != g) {
                unsafeAtomicAdd(&psum[(size_t)g * 128 + c], a);
                a = 0.f;
                g = gi;
            }
            a += Zs[i * 128 + c];
        }
        unsafeAtomicAdd(&psum[(size_t)g * 128 + c], a);
    }
}

// t1 = (psum/cnt) @ W_lin1 + b ; stats1 += (sum, sumsq)
__global__ __launch_bounds__(256) void lin1_kernel(const float* __restrict__ psum,
                                                   const int* __restrict__ gstart,
                                                   const float* __restrict__ W,
                                                   const float* __restrict__ bias,
                                                   float* __restrict__ t1,
                                                   float* __restrict__ stats1) {
    __shared__ float ls[256], ls2[256];
    int tid = threadIdx.x;
    int r = blockIdx.x * 4 + (tid >> 6);
    int c = tid & 63;
    float invc = 1.0f / fmaxf((float)(gstart[r + 1] - gstart[r]), 1.0f);
    float acc = 0.f;
    const float* srow = psum + (size_t)r * 128;
#pragma unroll 8
    for (int k = 0; k < 128; ++k)
        acc += srow[k] * W[k * 64 + c];
    acc = bias[c] + acc * invc;
    t1[r * 64 + c] = acc;
    ls[tid] = acc; ls2[tid] = acc * acc;
    __syncthreads();
    if (tid < 64) {
        float s = ls[tid] + ls[tid + 64] + ls[tid + 128] + ls[tid + 192];
        float q = ls2[tid] + ls2[tid + 64] + ls2[tid + 128] + ls2[tid + 192];
        unsafeAtomicAdd(&stats1[c], s);
        unsafeAtomicAdd(&stats1[64 + c], q);
    }
}

// t2 = relu(bn(t1; g2,be2)) @ W_lin2 + b ; stats2
__global__ __launch_bounds__(256) void lin2_kernel(const float* __restrict__ t1,
                                                   const float* __restrict__ stats1,
                                                   const float* __restrict__ g,
                                                   const float* __restrict__ be,
                                                   const float* __restrict__ W,
                                                   const float* __restrict__ bias,
                                                   float* __restrict__ t2,
                                                   float* __restrict__ stats2) {
    __shared__ float sc[64], sh[64];
    __shared__ float ls[256], ls2[256];
    int tid = threadIdx.x;
    if (tid < 64) {
        float m = stats1[tid] * (1.0f / BSZ);
        float var = stats1[64 + tid] * (1.0f / BSZ) - m * m;
        float s = g[tid] * rsqrtf(var + EPS);
        sc[tid] = s; sh[tid] = be[tid] - m * s;
    }
    __syncthreads();
    int r = blockIdx.x * 4 + (tid >> 6);
    int c = tid & 63;
    float acc = bias[c];
    const float* row = t1 + (size_t)r * 64;
#pragma unroll 8
    for (int k = 0; k < 64; ++k) {
        float z = fmaxf(row[k] * sc[k] + sh[k], 0.f);
        acc += z * W[k * 64 + c];
    }
    t2[r * 64 + c] = acc;
    ls[tid] = acc; ls2[tid] = acc * acc;
    __syncthreads();
    if (tid < 64) {
        float s = ls[tid] + ls[tid + 64] + ls[tid + 128] + ls[tid + 192];
        float q = ls2[tid] + ls2[tid + 64] + ls2[tid + 128] + ls2[tid + 192];
        unsafeAtomicAdd(&stats2[c], s);
        unsafeAtomicAdd(&stats2[64 + c], q);
    }
}

// t4 = concat(x, bn(t2;g3,be3)[masks]) @ W_fc1 + b ; stats4
__global__ __launch_bounds__(1024) void fc1_kernel(const float* __restrict__ x,
                                                   const int* __restrict__ masks,
                                                   const float* __restrict__ t2,
                                                   const float* __restrict__ stats2,
                                                   const float* __restrict__ g3,
                                                   const float* __restrict__ be3,
                                                   const float* __restrict__ W,
                                                   const float* __restrict__ bias,
                                                   float* __restrict__ t4,
                                                   float* __restrict__ stats4) {
    __shared__ float sc[64], sh[64];
    __shared__ float cat[4][128];
    __shared__ float ls[1024], ls2[1024];
    int tid = threadIdx.x;
    if (tid < 64) {
        float m = stats2[tid] * (1.0f / BSZ);
        float var = stats2[64 + tid] * (1.0f / BSZ) - m * m;
        float s = g3[tid] * rsqrtf(var + EPS);
        sc[tid] = s; sh[tid] = be3[tid] - m * s;
    }
    __syncthreads();
    int r0 = blockIdx.x * 4;
    if (tid < 512) {
        int i = tid >> 7;
        int k = tid & 127;
        int r = r0 + i;
        float v;
        if (k < 64) {
            v = x[r * 64 + k];
        } else {
            int mrow = masks[r];
            int kk = k - 64;
            v = t2[mrow * 64 + kk] * sc[kk] + sh[kk];
        }
        cat[i][k] = v;
    }
    __syncthreads();
    int i = tid >> 8;
    int c = tid & 255;
    float acc = bias[c];
#pragma unroll 8
    for (int k = 0; k < 128; ++k)
        acc += cat[i][k] * W[k * 256 + c];
    t4[(size_t)(r0 + i) * 256 + c] = acc;
    ls[tid] = acc; ls2[tid] = acc * acc;
    __syncthreads();
    if (tid < 256) {
        float s = ls[tid] + ls[tid + 256] + ls[tid + 512] + ls[tid + 768];
        float q = ls2[tid] + ls2[tid + 256] + ls2[tid + 512] + ls2[tid + 768];
        unsafeAtomicAdd(&stats4[c], s);
        unsafeAtomicAdd(&stats4[256 + c], q);
    }
}

// t5 = (relu(bn(t4;g4,be4))^2) @ W_fc2 + b ; stats5
__global__ __launch_bounds__(256) void fc2_kernel(const float* __restrict__ t4,
                                                  const float* __restrict__ stats4,
                                                  const float* __restrict__ g4,
                                                  const float* __restrict__ be4,
                                                  const float* __restrict__ W,
                                                  const float* __restrict__ bias,
                                                  float* __restrict__ t5,
                                                  float* __restrict__ stats5) {
    __shared__ float sc[256], sh[256];
    __shared__ float ls[256], ls2[256];
    int tid = threadIdx.x;
    {
        float m = stats4[tid] * (1.0f / BSZ);
        float var = stats4[256 + tid] * (1.0f / BSZ) - m * m;
        float s = g4[tid] * rsqrtf(var + EPS);
        sc[tid] = s; sh[tid] = be4[tid] - m * s;
    }
    __syncthreads();
    int r = blockIdx.x * 4 + (tid >> 6);
    int c = tid & 63;
    float acc = bias[c];
    const float* row = t4 + (size_t)r * 256;
#pragma unroll 8
    for (int k = 0; k < 256; ++k) {
        float z = fmaxf(row[k] * sc[k] + sh[k], 0.f);
        z *= z;
        acc += z * W[k * 64 + c];
    }
    t5[r * 64 + c] = acc;
    ls[tid] = acc; ls2[tid] = acc * acc;
    __syncthreads();
    if (tid < 64) {
        float s = ls[tid] + ls[tid + 64] + ls[tid + 128] + ls[tid + 192];
        float q = ls2[tid] + ls2[tid + 64] + ls2[tid + 128] + ls2[tid + 192];
        unsafeAtomicAdd(&stats5[c], s);
        unsafeAtomicAdd(&stats5[64 + c], q);
    }
}

// out = ((relu(bn(t5;g5,be5)))^4) @ W_fc3 + b
__global__ __launch_bounds__(256) void fc3_kernel(const float* __restrict__ t5,
                                                  const float* __restrict__ stats5,
                                                  const float* __restrict__ g5,
                                                  const float* __restrict__ be5,
                                                  const float* __restrict__ W,
                                                  const float* __restrict__ bias,
                                                  float* __restrict__ out) {
    __shared__ float sc[64], sh[64];
    int tid = threadIdx.x;
    if (tid < 64) {
        float m = stats5[tid] * (1.0f / BSZ);
        float var = stats5[64 + tid] * (1.0f / BSZ) - m * m;
        float s = g5[tid] * rsqrtf(var + EPS);
        sc[tid] = s; sh[tid] = be5[tid] - m * s;
    }
    __syncthreads();
    int r = blockIdx.x * 256 + tid;
    float acc = bias[0];
    const float* row = t5 + (size_t)r * 64;
#pragma unroll
    for (int k = 0; k < 64; ++k) {
        float z = fmaxf(row[k] * sc[k] + sh[k], 0.f);
        z = z * z;
        z = z * z;
        acc += z * W[k];
    }
    out[r] = acc;
}

extern "C" void kernel_launch(void* const* d_in, const int* in_sizes, int n_in,
                              void* d_out, int out_size, void* d_ws, size_t ws_size,
                              hipStream_t stream) {
    const float* x      = (const float*)d_in[0];
    const int*   masks  = (const int*)d_in[1];
    const float* gnn_x  = (const float*)d_in[2];
    const int*   ei     = (const int*)d_in[3];
    const int*   gbatch = (const int*)d_in[4];
    const float* W_gcn  = (const float*)d_in[5];
    const float* b_gcn  = (const float*)d_in[6];   // cancels in folded BN1
    const float* g1     = (const float*)d_in[7];
    const float* be1    = (const float*)d_in[8];
    const float* W_lin1 = (const float*)d_in[9];
    const float* b_lin1 = (const float*)d_in[10];
    const float* g2     = (const float*)d_in[11];
    const float* be2    = (const float*)d_in[12];
    const float* W_lin2 = (const float*)d_in[13];
    const float* b_lin2 = (const float*)d_in[14];
    const float* g3     = (const float*)d_in[15];
    const float* be3    = (const float*)d_in[16];
    const float* W_fc1  = (const float*)d_in[17];
    const float* b_fc1  = (const float*)d_in[18];
    const float* g4     = (const float*)d_in[19];
    const float* be4    = (const float*)d_in[20];
    const float* W_fc2  = (const float*)d_in[21];
    const float* b_fc2  = (const float*)d_in[22];
    const float* g5     = (const float*)d_in[23];
    const float* be5    = (const float*)d_in[24];
    const float* W_fc3  = (const float*)d_in[25];
    const float* b_fc3  = (const float*)d_in[26];
    (void)b_gcn;

    float* ws = (float*)d_ws;
    float* psum   = ws + WS_PSUM;
    float* stats1 = ws + WS_STATS1;
    float* stats2 = ws + WS_STATS2;
    float* stats4 = ws + WS_STATS4;
    float* stats5 = ws + WS_STATS5;
    float* Mbuf   = ws + WS_M;
    float* CSbuf  = ws + WS_CS;
    int*   gcur   = (int*)(ws + WS_GCUR);
    float* scale1 = ws + WS_SCALE1;
    float* shiftp = ws + WS_SHIFTP;
    int*   gstart = (int*)(ws + WS_GSTART);
    float* dis    = ws + WS_DIS;
    int*   rowptr = (int*)(ws + WS_ROWPTR);
    int*   rowlen = (int*)(ws + WS_ROWLEN);
    unsigned int* packed = (unsigned int*)(ws + WS_PACKED);
    int*   csrc   = (int*)(ws + WS_CSRC);
    unsigned short* xh   = (unsigned short*)(ws + WS_XH);
    unsigned short* aggx = (unsigned short*)(ws + WS_AGGX);
    float* t1     = ws + WS_T1;
    float* t2     = ws + WS_T2;
    float* t4     = ws + WS_T4;
    float* t5     = ws + WS_T5;
    float* out    = (float*)d_out;

    prep_cvt_kernel<<<CVT_BLOCKS + 21, 256, 0, stream>>>(ws, gbatch, gnn_x, xh);
    bin_kernel<<<BIN_BLOCKS, 512, 0, stream>>>(ei, gcur, packed);
    csr_build_kernel<<<NBUCK, 512, 0, stream>>>(packed, gcur, rowptr, rowlen, csrc, dis);
    gather_kernel<<<(N_NODES * 64 + 255) / 256, 256, 0, stream>>>(xh, rowptr, rowlen, csrc, dis, aggx);
    moment_kernel<<<NCHUNK, 256, 0, stream>>>(aggx, Mbuf, CSbuf);
    fold_kernel<<<128, 64, 0, stream>>>(Mbuf, CSbuf, W_gcn, g1, be1, scale1, shiftp);
    gemm_pool_kernel<<<N_NODES / 16, 256, 0, stream>>>(aggx, gbatch, W_gcn, scale1, shiftp, psum);
    lin1_kernel<<<256, 256, 0, stream>>>(psum, gstart, W_lin1, b_lin1, t1, stats1);
    lin2_kernel<<<256, 256, 0, stream>>>(t1, stats1, g2, be2, W_lin2, b_lin2, t2, stats2);
    fc1_kernel<<<256, 1024, 0, stream>>>(x, masks, t2, stats2, g3, be3, W_fc1, b_fc1, t4, stats4);
    fc2_kernel<<<256, 256, 0, stream>>>(t4, stats4, g4, be4, W_fc2, b_fc2, t5, stats5);
    fc3_kernel<<<4, 256, 0, stream>>>(t5, stats5, g5, be5, W_fc3, b_fc3, out);
}